// Round 6
// baseline (654.702 us; speedup 1.0000x reference)
//
#include <hip/hip_runtime.h>
#include <hip/hip_bf16.h>

typedef __bf16 bf16;
typedef __bf16 bf16x8 __attribute__((ext_vector_type(8)));
typedef __bf16 bf16x4 __attribute__((ext_vector_type(4)));
typedef float  f32x4  __attribute__((ext_vector_type(4)));

// ---------------------------------------------------------------------------
// raw barrier: flush LDS writes, DO NOT drain vmcnt (loads stay in flight)
// ---------------------------------------------------------------------------
__device__ __forceinline__ void block_barrier()
{
    asm volatile("s_waitcnt lgkmcnt(0)\n\ts_barrier" ::: "memory");
}

// ---------------------------------------------------------------------------
// async global->LDS 16B per lane: LDS dst = wave-uniform base + lane*16B
// ---------------------------------------------------------------------------
#if defined(__has_builtin)
#if __has_builtin(__builtin_amdgcn_global_load_lds)
#define HAS_GLD 1
#endif
#endif
#ifndef HAS_GLD
#define HAS_GLD 0
#endif

__device__ __forceinline__ void gld_lds16(const bf16* g, bf16* lds_base)
{
#if HAS_GLD
    __builtin_amdgcn_global_load_lds(
        (const __attribute__((address_space(1))) void*)g,
        (__attribute__((address_space(3))) void*)lds_base, 16, 0, 0);
#else
    *(bf16x8*)(lds_base + (threadIdx.x & 63) * 8) = *(const bf16x8*)g;
#endif
}

// ---------------------------------------------------------------------------
// Weight transpose + fp32->bf16: src (K,N) row-major -> dst (N,K)
// ---------------------------------------------------------------------------
__global__ __launch_bounds__(256)
void transpose_cvt(const float* __restrict__ src, bf16* __restrict__ dst, int K, int N)
{
    __shared__ float t[32][33];
    const int bx = blockIdx.x, by = blockIdx.y, tid = threadIdx.x;
    const int c = tid & 31, r0 = tid >> 5;
#pragma unroll
    for (int p = 0; p < 4; p++) {
        int r = r0 + p * 8;
        t[r][c] = src[(size_t)(by * 32 + r) * N + bx * 32 + c];
    }
    __syncthreads();
#pragma unroll
    for (int p = 0; p < 4; p++) {
        int r = r0 + p * 8;
        dst[(size_t)(bx * 32 + r) * K + by * 32 + c] = (bf16)t[c][r];
    }
}

// ---------------------------------------------------------------------------
// plain fp32 -> bf16 convert, 8 elems/thread
// ---------------------------------------------------------------------------
__global__ __launch_bounds__(256)
void cvt_bf16(const float* __restrict__ src, bf16* __restrict__ dst, int n8)
{
    const int i = blockIdx.x * 256 + threadIdx.x;
    if (i >= n8) return;
    const float4* s = (const float4*)(src + (size_t)i * 8);
    float4 a = s[0], b = s[1];
    bf16x8 o;
    o[0] = (bf16)a.x; o[1] = (bf16)a.y; o[2] = (bf16)a.z; o[3] = (bf16)a.w;
    o[4] = (bf16)b.x; o[5] = (bf16)b.y; o[6] = (bf16)b.z; o[7] = (bf16)b.w;
    *(bf16x8*)(dst + (size_t)i * 8) = o;
}

// ---------------------------------------------------------------------------
// m97-style GEMM: C = A @ B.  A bf16 (rows via ldA), Bt bf16 (N x K, ldB).
// 128x128 tile, BK=32, global_load_lds staging, XCD swizzle (gridDim.x==8).
// Optional A2 for concat-K (gate).
// ---------------------------------------------------------------------------
template<bool TWOA>
__global__ __launch_bounds__(256)
void gemm_a97(const bf16* __restrict__ A1, const bf16* __restrict__ A2,
              const bf16* __restrict__ Bt, float* __restrict__ Cf,
              bf16* __restrict__ Cb, int Kloop, int Ksplit,
              int ldA, int ldA2, int ldB, int ldC,
              long az, long bz, long cz)
{
    __shared__ bf16 Al[128 * 32];
    __shared__ bf16 Bl[128 * 32];

    const int z = blockIdx.z;
    A1 += (size_t)z * az;
    Bt += (size_t)z * bz;
    if (Cf) Cf += (size_t)z * cz;
    if (Cb) Cb += (size_t)z * cz;

    int bx, by;
    {
        const int gy = gridDim.y;
        const int flat = blockIdx.y * gridDim.x + blockIdx.x;
        if ((gy & 7) == 0 && gridDim.x == 8) {
            const int xcd = flat & 7, slot = flat >> 3, mpx = gy >> 3;
            by = xcd * mpx + (slot >> 3);
            bx = slot & 7;
        } else { bx = blockIdx.x; by = blockIdx.y; }
    }

    const int tid = threadIdx.x;
    const int wave = tid >> 6, lane = tid & 63;
    const int m0 = by * 128, n0 = bx * 128;
    const int rl = lane >> 2;
    const int kc = (lane & 3) * 8;
    const int wm = wave >> 1, wn = wave & 1, lm = lane & 15, quad = lane >> 4;

    f32x4 acc[4][4];
#pragma unroll
    for (int i = 0; i < 4; i++)
#pragma unroll
        for (int j = 0; j < 4; j++)
#pragma unroll
            for (int r = 0; r < 4; r++) acc[i][j][r] = 0.f;

    for (int k0 = 0; k0 < Kloop; k0 += 32) {
        const bf16* Ab; int kof, ld;
        if (TWOA && k0 >= Ksplit) { Ab = A2; kof = k0 - Ksplit; ld = ldA2; }
        else                      { Ab = A1; kof = k0;          ld = ldA;  }
        const int r0 = wave * 32 + rl, r1 = r0 + 16;
        gld_lds16(Ab + (size_t)(m0 + r0) * ld + kof + kc, Al + (wave * 32) * 32);
        gld_lds16(Ab + (size_t)(m0 + r1) * ld + kof + kc, Al + (wave * 32 + 16) * 32);
        gld_lds16(Bt + (size_t)(n0 + r0) * ldB + k0 + kc, Bl + (wave * 32) * 32);
        gld_lds16(Bt + (size_t)(n0 + r1) * ldB + k0 + kc, Bl + (wave * 32 + 16) * 32);
        __syncthreads();

        bf16x8 af[4], bfr[4];
#pragma unroll
        for (int i = 0; i < 4; i++)
            af[i] = *(const bf16x8*)&Al[(wm * 64 + i * 16 + lm) * 32 + quad * 8];
#pragma unroll
        for (int j = 0; j < 4; j++)
            bfr[j] = *(const bf16x8*)&Bl[(wn * 64 + j * 16 + lm) * 32 + quad * 8];
#pragma unroll
        for (int i = 0; i < 4; i++)
#pragma unroll
            for (int j = 0; j < 4; j++)
                acc[i][j] = __builtin_amdgcn_mfma_f32_16x16x32_bf16(af[i], bfr[j], acc[i][j], 0, 0, 0);
        __syncthreads();
    }

#pragma unroll
    for (int i = 0; i < 4; i++) {
        const int rbase = m0 + wm * 64 + i * 16 + quad * 4;
#pragma unroll
        for (int j = 0; j < 4; j++) {
            const int c = n0 + wn * 64 + j * 16 + lm;
#pragma unroll
            for (int r = 0; r < 4; r++) {
                const float v = acc[i][j][r];
                const size_t idx = (size_t)(rbase + r) * ldC + c;
                if (Cf) Cf[idx] = v;
                if (Cb) Cb[idx] = (bf16)v;
            }
        }
    }
}

// ---------------------------------------------------------------------------
// Weight-stationary partial-score kernel (unchanged from R4, verified).
// ---------------------------------------------------------------------------
__global__ __launch_bounds__(512, 4)
void score_attn_part(const bf16* __restrict__ Qb, const bf16* __restrict__ Wkb,
                     const float* __restrict__ mk, float* __restrict__ part)
{
    __shared__ bf16 Ul[16 * 1024];   // 32KB [b16][h16][64i] swz ^(((b^h)&7)<<4)

    const int tid  = threadIdx.x;
    const int wave = tid >> 6, lane = tid & 63;
    const int lm = lane & 15, q = lane >> 4;
    const int g  = blockIdx.x;       // b-group: rows [g*128, g*128+128)
    const int c  = blockIdx.y;       // i-chunk: i in [c*64, c*64+64)
    const int i0 = c * 64;
    const int h0 = wave * 2;

    // ---- weight-stationary Wk fragments (16 bf16x8 = 64 VGPR), loaded once
    bf16x8 wk[2][4][2];
#pragma unroll
    for (int hh = 0; hh < 2; hh++)
#pragma unroll
        for (int mt = 0; mt < 4; mt++) {
            const bf16* wp = Wkb + (size_t)(i0 + mt * 16 + lm) * 1024 + (h0 + hh) * 64 + q * 8;
            wk[hh][mt][0] = *(const bf16x8*)(wp);
            wk[hh][mt][1] = *(const bf16x8*)(wp + 32);
        }

    float* pbase = part + ((size_t)c << 20);   // c * 8192*128

    for (int t = 0; t < 8; ++t) {
        const int b0 = g * 128 + t * 16;

        // ---- Q B-frags for this b-tile (rows = b, K = d)
        bf16x8 qf[2][2];
#pragma unroll
        for (int hh = 0; hh < 2; hh++) {
            const bf16* qp = Qb + (size_t)(b0 + lm) * 1024 + (h0 + hh) * 64 + q * 8;
            qf[hh][0] = *(const bf16x8*)(qp);
            qf[hh][1] = *(const bf16x8*)(qp + 32);
        }

        // ---- U-gen: C[i][b] tiles -> Ul
#pragma unroll
        for (int hh = 0; hh < 2; hh++) {
            const int h = h0 + hh;
#pragma unroll
            for (int mt = 0; mt < 4; mt++) {
                f32x4 c4;
                c4[0] = 0.f; c4[1] = 0.f; c4[2] = 0.f; c4[3] = 0.f;
                c4 = __builtin_amdgcn_mfma_f32_16x16x32_bf16(wk[hh][mt][0], qf[hh][0], c4, 0, 0, 0);
                c4 = __builtin_amdgcn_mfma_f32_16x16x32_bf16(wk[hh][mt][1], qf[hh][1], c4, 0, 0, 0);
                bf16x4 o;
                o[0] = (bf16)c4[0]; o[1] = (bf16)c4[1]; o[2] = (bf16)c4[2]; o[3] = (bf16)c4[3];
                *(bf16x4*)((char*)Ul + ((((lm * 16 + h) * 64 + mt * 16 + q * 4) * 2)
                                        ^ (((lm ^ h) & 7) << 4))) = o;
            }
        }
        __syncthreads();

        // ---- score: wave's 2 rows; mk B-frags direct from global (+cvt)
#pragma unroll
        for (int lb = 0; lb < 2; lb++) {
            const int bb = wave * 2 + lb;
            const float* mp = mk + (size_t)(b0 + bb) * 8192 + (lm & 7) * 1024 + i0 + q * 8;
            const f32x4 a0 = *(const f32x4*)(mp);
            const f32x4 a1 = *(const f32x4*)(mp + 4);
            const f32x4 b0v = *(const f32x4*)(mp + 32);
            const f32x4 b1v = *(const f32x4*)(mp + 36);
            bf16x8 m0, m1;
            m0[0] = (bf16)a0[0]; m0[1] = (bf16)a0[1]; m0[2] = (bf16)a0[2]; m0[3] = (bf16)a0[3];
            m0[4] = (bf16)a1[0]; m0[5] = (bf16)a1[1]; m0[6] = (bf16)a1[2]; m0[7] = (bf16)a1[3];
            m1[0] = (bf16)b0v[0]; m1[1] = (bf16)b0v[1]; m1[2] = (bf16)b0v[2]; m1[3] = (bf16)b0v[3];
            m1[4] = (bf16)b1v[0]; m1[5] = (bf16)b1v[1]; m1[6] = (bf16)b1v[2]; m1[7] = (bf16)b1v[3];

            const bf16x8 ua0 = *(const bf16x8*)((char*)Ul +
                ((((bb * 16 + lm) * 64 + q * 8) * 2) ^ (((bb ^ lm) & 7) << 4)));
            const bf16x8 ua1 = *(const bf16x8*)((char*)Ul +
                ((((bb * 16 + lm) * 64 + 32 + q * 8) * 2) ^ (((bb ^ lm) & 7) << 4)));

            f32x4 s4;
            s4[0] = 0.f; s4[1] = 0.f; s4[2] = 0.f; s4[3] = 0.f;
            s4 = __builtin_amdgcn_mfma_f32_16x16x32_bf16(ua0, m0, s4, 0, 0, 0);
            s4 = __builtin_amdgcn_mfma_f32_16x16x32_bf16(ua1, m1, s4, 0, 0, 0);

            // C[h=q*4+r][k=lm&7] for row b0+bb; lm>=8 is a duplicate
            if (lm < 8) {
                float* pp = pbase + (size_t)(b0 + bb) * 128 + lm;
#pragma unroll
                for (int r = 0; r < 4; r++) pp[(q * 4 + r) * 8] = s4[r];
            }
        }
        __syncthreads();
    }
}

// ---------------------------------------------------------------------------
// reduce 16 i-chunk partials + softmax over k -> attn (B x 16 x 8 fp32)
// ---------------------------------------------------------------------------
__global__ __launch_bounds__(256)
void reduce_softmax(const float* __restrict__ part, float* __restrict__ attn)
{
    const int t = blockIdx.x * 256 + threadIdx.x;   // (b*16 + h)
    const float* p = part + (size_t)t * 8;
    float s[8] = {0.f, 0.f, 0.f, 0.f, 0.f, 0.f, 0.f, 0.f};
#pragma unroll
    for (int c = 0; c < 16; ++c) {
        const f32x4 a = *(const f32x4*)(p + ((size_t)c << 20));
        const f32x4 b = *(const f32x4*)(p + ((size_t)c << 20) + 4);
        s[0] += a[0]; s[1] += a[1]; s[2] += a[2]; s[3] += a[3];
        s[4] += b[0]; s[5] += b[1]; s[6] += b[2]; s[7] += b[3];
    }
#pragma unroll
    for (int k = 0; k < 8; k++) s[k] *= 0.125f;     // DH^-0.5
    float mx = s[0];
#pragma unroll
    for (int k = 1; k < 8; k++) mx = fmaxf(mx, s[k]);
    float den = 0.f;
#pragma unroll
    for (int k = 0; k < 8; k++) { s[k] = __expf(s[k] - mx); den += s[k]; }
    const float inv = 1.f / den;
    f32x4 o0, o1;
    o0[0] = s[0] * inv; o0[1] = s[1] * inv; o0[2] = s[2] * inv; o0[3] = s[3] * inv;
    o1[0] = s[4] * inv; o1[1] = s[5] * inv; o1[2] = s[6] * inv; o1[3] = s[7] * inv;
    *(f32x4*)(attn + (size_t)t * 8)     = o0;
    *(f32x4*)(attn + (size_t)t * 8 + 4) = o1;
}

// ---------------------------------------------------------------------------
// Fused apply kernel v5: drain-free FIFO pipeline.
// Issue order == consume order: mv(sp) < wb0(sp) < wb1(sp) < mv(sp+1) < ...
// Per superstep: cvt mvp(sp) [vmcnt leaves Wvt(sp) in flight] -> issue
// mv(sp+1) -> Wm-gen -> lgkm-barrier -> OH0 (vmcnt(24)) -> issue wb0(sp+1)
// -> OH1 (vmcnt(24)) -> issue wb1(sp+1) -> lgkm-barrier.  No vmcnt(0) in
// the loop; mv always has a full superstep of latency cover.
// ---------------------------------------------------------------------------
__global__ __launch_bounds__(512, 4)
void apply_attn(const float* __restrict__ attn, const float* __restrict__ mv,
                const bf16* __restrict__ Wvt, bf16* __restrict__ OH)
{
    __shared__ bf16 Wl[16 * 1024];     // 32KB [b][h][64i] swz ^(((b^h)&7)<<4)

    const int tid  = threadIdx.x;
    const int wave = tid >> 6, lane = tid & 63;
    const int lm = lane & 15, q = lane >> 4;
    const int b0 = blockIdx.x * 16;
    const int h0 = wave * 2;

    // ---- attn B-frag variants: afv[lb][mt] nonzero only where q==mt
    bf16x8 afv[2][4];
#pragma unroll
    for (int lb = 0; lb < 2; lb++) {
        const float* ap = attn + (size_t)(b0 + wave * 2 + lb) * 128 + lm * 8;
        const float4 x = *(const float4*)(ap);
        const float4 y = *(const float4*)(ap + 4);
        bf16 a8[8];
        a8[0] = (bf16)x.x; a8[1] = (bf16)x.y; a8[2] = (bf16)x.z; a8[3] = (bf16)x.w;
        a8[4] = (bf16)y.x; a8[5] = (bf16)y.y; a8[6] = (bf16)y.z; a8[7] = (bf16)y.w;
#pragma unroll
        for (int mt = 0; mt < 4; mt++) {
            bf16x8 t;
#pragma unroll
            for (int j = 0; j < 8; j++) t[j] = (q == mt) ? a8[j] : (bf16)0.f;
            afv[lb][mt] = t;
        }
    }

    f32x4 oacc[2][4];
#pragma unroll
    for (int i = 0; i < 2; i++)
#pragma unroll
        for (int j = 0; j < 4; j++)
#pragma unroll
            for (int r = 0; r < 4; r++) oacc[i][j][r] = 0.f;

    const float* mp0 = mv + (size_t)(b0 + wave * 2 + 0) * 8192 + q * 16 + lm;
    const float* mp1 = mv + (size_t)(b0 + wave * 2 + 1) * 8192 + q * 16 + lm;

    // ---- prologue: issue mv(0) (oldest), then Wvt(0) batches 0 and 1
    float mvp[2][8];
#pragma unroll
    for (int k = 0; k < 8; k++) mvp[0][k] = mp0[k * 1024];
#pragma unroll
    for (int k = 0; k < 8; k++) mvp[1][k] = mp1[k * 1024];

    bf16x8 wbA[2][4], wbB[2][4];
#pragma unroll
    for (int hh = 0; hh < 2; hh++) {
        const int h = h0 + hh;
#pragma unroll
        for (int dt = 0; dt < 4; dt++)
            wbA[hh][dt] = *(const bf16x8*)(Wvt + (size_t)(h * 64 + dt * 16 + lm) * 1024 + q * 8);
    }
#pragma unroll
    for (int hh = 0; hh < 2; hh++) {
        const int h = h0 + hh;
#pragma unroll
        for (int dt = 0; dt < 4; dt++)
            wbB[hh][dt] = *(const bf16x8*)(Wvt + (size_t)(h * 64 + dt * 16 + lm) * 1024 + 32 + q * 8);
    }

    for (int sp = 0; sp < 16; ++sp) {
        const int i0 = sp * 64;
        const int ni = (sp == 15) ? i0 : i0 + 64;   // sp=15 reloads same (L2-hot)

        // 1. consume mvp(sp): cvt -> A-frags (waits mv(sp); Wvt(sp) stays in flight)
        bf16x8 avf[2];
#pragma unroll
        for (int lb = 0; lb < 2; lb++) {
            bf16x8 t;
#pragma unroll
            for (int k = 0; k < 8; k++) t[k] = (bf16)mvp[lb][k];
            avf[lb] = t;
        }
        // 2. issue mv(sp+1) into mvp (WAR after cvt)
#pragma unroll
        for (int k = 0; k < 8; k++) mvp[0][k] = mp0[ni + k * 1024];
#pragma unroll
        for (int k = 0; k < 8; k++) mvp[1][k] = mp1[ni + k * 1024];

        // 3. Wm-gen: one dense A-frag x 4 B-variants -> 4 C tiles -> Wl
#pragma unroll
        for (int lb = 0; lb < 2; lb++) {
            const int bb = wave * 2 + lb;
#pragma unroll
            for (int mt = 0; mt < 4; mt++) {
                f32x4 c;
                c[0] = 0.f; c[1] = 0.f; c[2] = 0.f; c[3] = 0.f;
                c = __builtin_amdgcn_mfma_f32_16x16x32_bf16(avf[lb], afv[lb][mt], c, 0, 0, 0);
                bf16x4 o;
                o[0] = (bf16)c[0]; o[1] = (bf16)c[1]; o[2] = (bf16)c[2]; o[3] = (bf16)c[3];
                *(bf16x4*)((char*)Wl + ((((bb * 16 + lm) * 64 + mt * 16 + q * 4) * 2)
                                        ^ (((bb ^ lm) & 7) << 4))) = o;
            }
        }
        block_barrier();   // Wl ready (lgkm only; all vmem stays in flight)

        // 4. OH it=0 (consumes wbA(sp); wbB(sp)+mv(sp+1) stay in flight)
#pragma unroll
        for (int hh = 0; hh < 2; hh++) {
            const int h = h0 + hh;
            const bf16x8 wa = *(const bf16x8*)((char*)Wl +
                ((((lm * 16 + h) * 64 + q * 8) * 2) ^ (((lm ^ h) & 7) << 4)));
#pragma unroll
            for (int dt = 0; dt < 4; dt++)
                oacc[hh][dt] = __builtin_amdgcn_mfma_f32_16x16x32_bf16(wa, wbA[hh][dt], oacc[hh][dt], 0, 0, 0);
        }
        // 5. issue Wvt batch0(sp+1) into wbA (WAR after step 4 reads)
#pragma unroll
        for (int hh = 0; hh < 2; hh++) {
            const int h = h0 + hh;
#pragma unroll
            for (int dt = 0; dt < 4; dt++)
                wbA[hh][dt] = *(const bf16x8*)(Wvt + (size_t)(h * 64 + dt * 16 + lm) * 1024 + ni + q * 8);
        }
        // 6. OH it=1 (consumes wbB(sp); wbA(sp+1)+mv(sp+1) stay in flight)
#pragma unroll
        for (int hh = 0; hh < 2; hh++) {
            const int h = h0 + hh;
            const bf16x8 wa = *(const bf16x8*)((char*)Wl +
                ((((lm * 16 + h) * 64 + 32 + q * 8) * 2) ^ (((lm ^ h) & 7) << 4)));
#pragma unroll
            for (int dt = 0; dt < 4; dt++)
                oacc[hh][dt] = __builtin_amdgcn_mfma_f32_16x16x32_bf16(wa, wbB[hh][dt], oacc[hh][dt], 0, 0, 0);
        }
        // 7. issue Wvt batch1(sp+1) into wbB
#pragma unroll
        for (int hh = 0; hh < 2; hh++) {
            const int h = h0 + hh;
#pragma unroll
            for (int dt = 0; dt < 4; dt++)
                wbB[hh][dt] = *(const bf16x8*)(Wvt + (size_t)(h * 64 + dt * 16 + lm) * 1024 + ni + 32 + q * 8);
        }
        block_barrier();   // Wl consumed; safe to overwrite next superstep
    }

    // store OH (rows b = q*4+r, cols h*64 + dt*16 + lm)
#pragma unroll
    for (int hh = 0; hh < 2; hh++) {
        const int h = h0 + hh;
#pragma unroll
        for (int dt = 0; dt < 4; dt++) {
#pragma unroll
            for (int r = 0; r < 4; r++)
                OH[(size_t)(b0 + q * 4 + r) * 1024 + h * 64 + dt * 16 + lm] = (bf16)oacc[hh][dt][r];
        }
    }
}

// ---------------------------------------------------------------------------
// sigmoid gate + residual + LayerNorm. One block per row.
// ---------------------------------------------------------------------------
__global__ __launch_bounds__(256)
void gate_ln_kernel(const float* __restrict__ hs, const float* __restrict__ mo,
                    const float* __restrict__ z,  const float* __restrict__ bg,
                    const float* __restrict__ lng, const float* __restrict__ lnb,
                    float* __restrict__ out)
{
    __shared__ float s1[4], s2[4];
    const int tid = threadIdx.x;
    const size_t base = (size_t)blockIdx.x * 1024 + tid * 4;

    const float4 h4 = *(const float4*)&hs[base];
    const float4 m4 = *(const float4*)&mo[base];
    const float4 z4 = *(const float4*)&z[base];
    const float4 bg4 = *(const float4*)&bg[tid * 4];

    float a[4];
    {
        const float g0 = 1.f / (1.f + __expf(-(z4.x + bg4.x)));
        const float g1 = 1.f / (1.f + __expf(-(z4.y + bg4.y)));
        const float g2 = 1.f / (1.f + __expf(-(z4.z + bg4.z)));
        const float g3 = 1.f / (1.f + __expf(-(z4.w + bg4.w)));
        a[0] = h4.x + g0 * m4.x;
        a[1] = h4.y + g1 * m4.y;
        a[2] = h4.z + g2 * m4.z;
        a[3] = h4.w + g3 * m4.w;
    }
    float sum = a[0] + a[1] + a[2] + a[3];
    float sq  = a[0]*a[0] + a[1]*a[1] + a[2]*a[2] + a[3]*a[3];
#pragma unroll
    for (int off = 32; off >= 1; off >>= 1) {
        sum += __shfl_xor(sum, off);
        sq  += __shfl_xor(sq,  off);
    }
    const int wave = tid >> 6;
    if ((tid & 63) == 0) { s1[wave] = sum; s2[wave] = sq; }
    __syncthreads();
    const float mean = (s1[0] + s1[1] + s1[2] + s1[3]) * (1.f / 1024.f);
    const float var  = (s2[0] + s2[1] + s2[2] + s2[3]) * (1.f / 1024.f) - mean * mean;
    const float inv  = rsqrtf(var + 1e-5f);

    const float4 g4 = *(const float4*)&lng[tid * 4];
    const float4 b4 = *(const float4*)&lnb[tid * 4];
    float4 o;
    o.x = (a[0] - mean) * inv * g4.x + b4.x;
    o.y = (a[1] - mean) * inv * g4.y + b4.y;
    o.z = (a[2] - mean) * inv * g4.z + b4.z;
    o.w = (a[3] - mean) * inv * g4.w + b4.w;
    *(float4*)&out[base] = o;
}

// ---------------------------------------------------------------------------
extern "C" void kernel_launch(void* const* d_in, const int* in_sizes, int n_in,
                              void* d_out, int out_size, void* d_ws, size_t ws_size,
                              hipStream_t stream)
{
    const float* hs  = (const float*)d_in[0];
    const float* mk  = (const float*)d_in[1];
    const float* mv  = (const float*)d_in[2];
    const float* Wq  = (const float*)d_in[3];
    const float* Wk  = (const float*)d_in[4];
    const float* Wv  = (const float*)d_in[5];
    const float* Wo  = (const float*)d_in[6];
    const float* Wg  = (const float*)d_in[7];
    const float* bg  = (const float*)d_in[8];
    const float* lng = (const float*)d_in[9];
    const float* lnb = (const float*)d_in[10];
    float* out = (float*)d_out;

    const int B = 8192;
    const dim3 tb(256);

    char* ws = (char*)d_ws;
    bf16*  Wq_t = (bf16*)(ws);                        // 2 MB  (1024x1024, N x K)
    bf16*  Wv_t = (bf16*)(ws + ((size_t)2  << 20));   // 2 MB
    bf16*  Wo_t = (bf16*)(ws + ((size_t)4  << 20));   // 2 MB
    bf16*  Wg_t = (bf16*)(ws + ((size_t)6  << 20));   // 4 MB  (1024x2048)
    bf16*  Wk_b = (bf16*)(ws + ((size_t)10 << 20));   // 2 MB  (1024x1024, NOT transposed)
    bf16*  hs_b = (bf16*)(ws + ((size_t)12 << 20));   // 16 MB (8192x1024)
    bf16*  Qb   = (bf16*)(ws + ((size_t)28 << 20));   // 16 MB
    bf16*  OH   = (bf16*)(ws + ((size_t)44 << 20));   // 16 MB
    float* Mo   = (float*)(ws + ((size_t)60 << 20));  // 32 MB
    bf16*  Mo_b = (bf16*)(ws + ((size_t)92 << 20));   // 16 MB
    float* Zb   = (float*)(ws + ((size_t)108 << 20)); // 32 MB
    float* At   = (float*)(ws + ((size_t)140 << 20)); // 4 MB  (8192x16x8 fp32)
    float* Atp  = (float*)(ws + ((size_t)144 << 20)); // 64 MB (16 x 8192x16x8 fp32)

    transpose_cvt<<<dim3(32, 32), tb, 0, stream>>>(Wq, Wq_t, 1024, 1024);
    transpose_cvt<<<dim3(32, 32), tb, 0, stream>>>(Wv, Wv_t, 1024, 1024);
    transpose_cvt<<<dim3(32, 32), tb, 0, stream>>>(Wo, Wo_t, 1024, 1024);
    transpose_cvt<<<dim3(32, 64), tb, 0, stream>>>(Wg, Wg_t, 2048, 1024);
    cvt_bf16<<<dim3(1024 * 1024 / 8 / 256), tb, 0, stream>>>(Wk, Wk_b, 1024 * 1024 / 8);
    cvt_bf16<<<dim3(B * 1024 / 8 / 256), tb, 0, stream>>>(hs, hs_b, B * 1024 / 8);

    // Q = hs @ Wq -> bf16 (B x 1024)
    gemm_a97<false><<<dim3(8, 64, 1), tb, 0, stream>>>(
        hs_b, nullptr, Wq_t, nullptr, Qb,
        1024, 1024, 1024, 0, 1024, 1024, 0, 0, 0);
    // weight-stationary partial scores (16 i-chunks x 64 b-groups)
    score_attn_part<<<dim3(64, 16), dim3(512), 0, stream>>>(Qb, Wk_b, mk, Atp);
    // reduce chunks + softmax -> attn
    reduce_softmax<<<dim3(512), tb, 0, stream>>>(Atp, At);
    // fused: W_mix-gen + V-proj -> OH (B x 1024 bf16)
    apply_attn<<<dim3(B / 16), dim3(512), 0, stream>>>(At, mv, Wv_t, OH);
    // memory_out = OH @ Wo -> fp32 Mo + bf16 Mo_b
    gemm_a97<false><<<dim3(8, 64, 1), tb, 0, stream>>>(
        OH, nullptr, Wo_t, Mo, Mo_b,
        1024, 1024, 1024, 0, 1024, 1024, 0, 0, 0);
    // z = [hs, Mo] @ Wg -> fp32
    gemm_a97<true><<<dim3(8, 64, 1), tb, 0, stream>>>(
        hs_b, Mo_b, Wg_t, Zb, nullptr,
        2048, 1024, 1024, 1024, 2048, 1024, 0, 0, 0);
    // gate + residual + LayerNorm
    gate_ln_kernel<<<dim3(B), tb, 0, stream>>>(
        hs, Mo, Zb, bg, lng, lnb, out);
}

// Round 7
// 554.543 us; speedup vs baseline: 1.1806x; 1.1806x over previous
//
#include <hip/hip_runtime.h>
#include <hip/hip_bf16.h>

typedef __bf16 bf16;
typedef __bf16 bf16x8 __attribute__((ext_vector_type(8)));
typedef __bf16 bf16x4 __attribute__((ext_vector_type(4)));
typedef float  f32x4  __attribute__((ext_vector_type(4)));

// ---------------------------------------------------------------------------
// raw barrier: flush LDS writes, DO NOT drain vmcnt (loads stay in flight)
// ---------------------------------------------------------------------------
__device__ __forceinline__ void block_barrier()
{
    asm volatile("s_waitcnt lgkmcnt(0)\n\ts_barrier" ::: "memory");
}

// ---------------------------------------------------------------------------
// async global->LDS 16B per lane: LDS dst = wave-uniform base + lane*16B
// ---------------------------------------------------------------------------
#if defined(__has_builtin)
#if __has_builtin(__builtin_amdgcn_global_load_lds)
#define HAS_GLD 1
#endif
#endif
#ifndef HAS_GLD
#define HAS_GLD 0
#endif

__device__ __forceinline__ void gld_lds16(const bf16* g, bf16* lds_base)
{
#if HAS_GLD
    __builtin_amdgcn_global_load_lds(
        (const __attribute__((address_space(1))) void*)g,
        (__attribute__((address_space(3))) void*)lds_base, 16, 0, 0);
#else
    *(bf16x8*)(lds_base + (threadIdx.x & 63) * 8) = *(const bf16x8*)g;
#endif
}

// ---------------------------------------------------------------------------
// Weight transpose + fp32->bf16: src (K,N) row-major -> dst (N,K) w/ stride Kd
// ---------------------------------------------------------------------------
__global__ __launch_bounds__(256)
void transpose_cvt(const float* __restrict__ src, bf16* __restrict__ dst, int K, int N)
{
    __shared__ float t[32][33];
    const int bx = blockIdx.x, by = blockIdx.y, tid = threadIdx.x;
    const int c = tid & 31, r0 = tid >> 5;
#pragma unroll
    for (int p = 0; p < 4; p++) {
        int r = r0 + p * 8;
        t[r][c] = src[(size_t)(by * 32 + r) * N + bx * 32 + c];
    }
    __syncthreads();
#pragma unroll
    for (int p = 0; p < 4; p++) {
        int r = r0 + p * 8;
        dst[(size_t)(bx * 32 + r) * K + by * 32 + c] = (bf16)t[c][r];
    }
}

// ---------------------------------------------------------------------------
// plain fp32 -> bf16 convert, 8 elems/thread
// ---------------------------------------------------------------------------
__global__ __launch_bounds__(256)
void cvt_bf16(const float* __restrict__ src, bf16* __restrict__ dst, int n8)
{
    const int i = blockIdx.x * 256 + threadIdx.x;
    if (i >= n8) return;
    const float4* s = (const float4*)(src + (size_t)i * 8);
    float4 a = s[0], b = s[1];
    bf16x8 o;
    o[0] = (bf16)a.x; o[1] = (bf16)a.y; o[2] = (bf16)a.z; o[3] = (bf16)a.w;
    o[4] = (bf16)b.x; o[5] = (bf16)b.y; o[6] = (bf16)b.z; o[7] = (bf16)b.w;
    *(bf16x8*)(dst + (size_t)i * 8) = o;
}

// ---------------------------------------------------------------------------
// m97-style GEMM: C = A @ B.  A bf16 (rows via ldA), Bt bf16 (N x K, ldB).
// 128x128 tile, BK=32, global_load_lds staging, XCD swizzle (gridDim.x==8).
// Optional A2 for concat-K (gate / OH-partial sum).
// ---------------------------------------------------------------------------
template<bool TWOA>
__global__ __launch_bounds__(256)
void gemm_a97(const bf16* __restrict__ A1, const bf16* __restrict__ A2,
              const bf16* __restrict__ Bt, float* __restrict__ Cf,
              bf16* __restrict__ Cb, int Kloop, int Ksplit,
              int ldA, int ldA2, int ldB, int ldC,
              long az, long bz, long cz)
{
    __shared__ bf16 Al[128 * 32];
    __shared__ bf16 Bl[128 * 32];

    const int z = blockIdx.z;
    A1 += (size_t)z * az;
    Bt += (size_t)z * bz;
    if (Cf) Cf += (size_t)z * cz;
    if (Cb) Cb += (size_t)z * cz;

    int bx, by;
    {
        const int gy = gridDim.y;
        const int flat = blockIdx.y * gridDim.x + blockIdx.x;
        if ((gy & 7) == 0 && gridDim.x == 8) {
            const int xcd = flat & 7, slot = flat >> 3, mpx = gy >> 3;
            by = xcd * mpx + (slot >> 3);
            bx = slot & 7;
        } else { bx = blockIdx.x; by = blockIdx.y; }
    }

    const int tid = threadIdx.x;
    const int wave = tid >> 6, lane = tid & 63;
    const int m0 = by * 128, n0 = bx * 128;
    const int rl = lane >> 2;
    const int kc = (lane & 3) * 8;
    const int wm = wave >> 1, wn = wave & 1, lm = lane & 15, quad = lane >> 4;

    f32x4 acc[4][4];
#pragma unroll
    for (int i = 0; i < 4; i++)
#pragma unroll
        for (int j = 0; j < 4; j++)
#pragma unroll
            for (int r = 0; r < 4; r++) acc[i][j][r] = 0.f;

    for (int k0 = 0; k0 < Kloop; k0 += 32) {
        const bf16* Ab; int kof, ld;
        if (TWOA && k0 >= Ksplit) { Ab = A2; kof = k0 - Ksplit; ld = ldA2; }
        else                      { Ab = A1; kof = k0;          ld = ldA;  }
        const int r0 = wave * 32 + rl, r1 = r0 + 16;
        gld_lds16(Ab + (size_t)(m0 + r0) * ld + kof + kc, Al + (wave * 32) * 32);
        gld_lds16(Ab + (size_t)(m0 + r1) * ld + kof + kc, Al + (wave * 32 + 16) * 32);
        gld_lds16(Bt + (size_t)(n0 + r0) * ldB + k0 + kc, Bl + (wave * 32) * 32);
        gld_lds16(Bt + (size_t)(n0 + r1) * ldB + k0 + kc, Bl + (wave * 32 + 16) * 32);
        __syncthreads();

        bf16x8 af[4], bfr[4];
#pragma unroll
        for (int i = 0; i < 4; i++)
            af[i] = *(const bf16x8*)&Al[(wm * 64 + i * 16 + lm) * 32 + quad * 8];
#pragma unroll
        for (int j = 0; j < 4; j++)
            bfr[j] = *(const bf16x8*)&Bl[(wn * 64 + j * 16 + lm) * 32 + quad * 8];
#pragma unroll
        for (int i = 0; i < 4; i++)
#pragma unroll
            for (int j = 0; j < 4; j++)
                acc[i][j] = __builtin_amdgcn_mfma_f32_16x16x32_bf16(af[i], bfr[j], acc[i][j], 0, 0, 0);
        __syncthreads();
    }

#pragma unroll
    for (int i = 0; i < 4; i++) {
        const int rbase = m0 + wm * 64 + i * 16 + quad * 4;
#pragma unroll
        for (int j = 0; j < 4; j++) {
            const int c = n0 + wn * 64 + j * 16 + lm;
#pragma unroll
            for (int r = 0; r < 4; r++) {
                const float v = acc[i][j][r];
                const size_t idx = (size_t)(rbase + r) * ldC + c;
                if (Cf) Cf[idx] = v;
                if (Cb) Cb[idx] = (bf16)v;
            }
        }
    }
}

// ---------------------------------------------------------------------------
// Weight-stationary partial-score kernel (unchanged, verified).
// ---------------------------------------------------------------------------
__global__ __launch_bounds__(512, 4)
void score_attn_part(const bf16* __restrict__ Qb, const bf16* __restrict__ Wkb,
                     const float* __restrict__ mk, float* __restrict__ part)
{
    __shared__ bf16 Ul[16 * 1024];   // 32KB [b16][h16][64i] swz ^(((b^h)&7)<<4)

    const int tid  = threadIdx.x;
    const int wave = tid >> 6, lane = tid & 63;
    const int lm = lane & 15, q = lane >> 4;
    const int g  = blockIdx.x;       // b-group: rows [g*128, g*128+128)
    const int c  = blockIdx.y;       // i-chunk: i in [c*64, c*64+64)
    const int i0 = c * 64;
    const int h0 = wave * 2;

    // ---- weight-stationary Wk fragments (16 bf16x8 = 64 VGPR), loaded once
    bf16x8 wk[2][4][2];
#pragma unroll
    for (int hh = 0; hh < 2; hh++)
#pragma unroll
        for (int mt = 0; mt < 4; mt++) {
            const bf16* wp = Wkb + (size_t)(i0 + mt * 16 + lm) * 1024 + (h0 + hh) * 64 + q * 8;
            wk[hh][mt][0] = *(const bf16x8*)(wp);
            wk[hh][mt][1] = *(const bf16x8*)(wp + 32);
        }

    float* pbase = part + ((size_t)c << 20);   // c * 8192*128

    for (int t = 0; t < 8; ++t) {
        const int b0 = g * 128 + t * 16;

        // ---- Q B-frags for this b-tile (rows = b, K = d)
        bf16x8 qf[2][2];
#pragma unroll
        for (int hh = 0; hh < 2; hh++) {
            const bf16* qp = Qb + (size_t)(b0 + lm) * 1024 + (h0 + hh) * 64 + q * 8;
            qf[hh][0] = *(const bf16x8*)(qp);
            qf[hh][1] = *(const bf16x8*)(qp + 32);
        }

        // ---- U-gen: C[i][b] tiles -> Ul
#pragma unroll
        for (int hh = 0; hh < 2; hh++) {
            const int h = h0 + hh;
#pragma unroll
            for (int mt = 0; mt < 4; mt++) {
                f32x4 c4;
                c4[0] = 0.f; c4[1] = 0.f; c4[2] = 0.f; c4[3] = 0.f;
                c4 = __builtin_amdgcn_mfma_f32_16x16x32_bf16(wk[hh][mt][0], qf[hh][0], c4, 0, 0, 0);
                c4 = __builtin_amdgcn_mfma_f32_16x16x32_bf16(wk[hh][mt][1], qf[hh][1], c4, 0, 0, 0);
                bf16x4 o;
                o[0] = (bf16)c4[0]; o[1] = (bf16)c4[1]; o[2] = (bf16)c4[2]; o[3] = (bf16)c4[3];
                *(bf16x4*)((char*)Ul + ((((lm * 16 + h) * 64 + mt * 16 + q * 4) * 2)
                                        ^ (((lm ^ h) & 7) << 4))) = o;
            }
        }
        __syncthreads();

        // ---- score: wave's 2 rows; mk B-frags direct from global (+cvt)
#pragma unroll
        for (int lb = 0; lb < 2; lb++) {
            const int bb = wave * 2 + lb;
            const float* mp = mk + (size_t)(b0 + bb) * 8192 + (lm & 7) * 1024 + i0 + q * 8;
            const f32x4 a0 = *(const f32x4*)(mp);
            const f32x4 a1 = *(const f32x4*)(mp + 4);
            const f32x4 b0v = *(const f32x4*)(mp + 32);
            const f32x4 b1v = *(const f32x4*)(mp + 36);
            bf16x8 m0, m1;
            m0[0] = (bf16)a0[0]; m0[1] = (bf16)a0[1]; m0[2] = (bf16)a0[2]; m0[3] = (bf16)a0[3];
            m0[4] = (bf16)a1[0]; m0[5] = (bf16)a1[1]; m0[6] = (bf16)a1[2]; m0[7] = (bf16)a1[3];
            m1[0] = (bf16)b0v[0]; m1[1] = (bf16)b0v[1]; m1[2] = (bf16)b0v[2]; m1[3] = (bf16)b0v[3];
            m1[4] = (bf16)b1v[0]; m1[5] = (bf16)b1v[1]; m1[6] = (bf16)b1v[2]; m1[7] = (bf16)b1v[3];

            const bf16x8 ua0 = *(const bf16x8*)((char*)Ul +
                ((((bb * 16 + lm) * 64 + q * 8) * 2) ^ (((bb ^ lm) & 7) << 4)));
            const bf16x8 ua1 = *(const bf16x8*)((char*)Ul +
                ((((bb * 16 + lm) * 64 + 32 + q * 8) * 2) ^ (((bb ^ lm) & 7) << 4)));

            f32x4 s4;
            s4[0] = 0.f; s4[1] = 0.f; s4[2] = 0.f; s4[3] = 0.f;
            s4 = __builtin_amdgcn_mfma_f32_16x16x32_bf16(ua0, m0, s4, 0, 0, 0);
            s4 = __builtin_amdgcn_mfma_f32_16x16x32_bf16(ua1, m1, s4, 0, 0, 0);

            // C[h=q*4+r][k=lm&7] for row b0+bb; lm>=8 is a duplicate
            if (lm < 8) {
                float* pp = pbase + (size_t)(b0 + bb) * 128 + lm;
#pragma unroll
                for (int r = 0; r < 4; r++) pp[(q * 4 + r) * 8] = s4[r];
            }
        }
        __syncthreads();
    }
}

// ---------------------------------------------------------------------------
// reduce 16 i-chunk partials + softmax over k -> attn (B x 16 x 8 fp32)
// ---------------------------------------------------------------------------
__global__ __launch_bounds__(256)
void reduce_softmax(const float* __restrict__ part, float* __restrict__ attn)
{
    const int t = blockIdx.x * 256 + threadIdx.x;   // (b*16 + h)
    const float* p = part + (size_t)t * 8;
    float s[8] = {0.f, 0.f, 0.f, 0.f, 0.f, 0.f, 0.f, 0.f};
#pragma unroll
    for (int c = 0; c < 16; ++c) {
        const f32x4 a = *(const f32x4*)(p + ((size_t)c << 20));
        const f32x4 b = *(const f32x4*)(p + ((size_t)c << 20) + 4);
        s[0] += a[0]; s[1] += a[1]; s[2] += a[2]; s[3] += a[3];
        s[4] += b[0]; s[5] += b[1]; s[6] += b[2]; s[7] += b[3];
    }
#pragma unroll
    for (int k = 0; k < 8; k++) s[k] *= 0.125f;     // DH^-0.5
    float mx = s[0];
#pragma unroll
    for (int k = 1; k < 8; k++) mx = fmaxf(mx, s[k]);
    float den = 0.f;
#pragma unroll
    for (int k = 0; k < 8; k++) { s[k] = __expf(s[k] - mx); den += s[k]; }
    const float inv = 1.f / den;
    f32x4 o0, o1;
    o0[0] = s[0] * inv; o0[1] = s[1] * inv; o0[2] = s[2] * inv; o0[3] = s[3] * inv;
    o1[0] = s[4] * inv; o1[1] = s[5] * inv; o1[2] = s[6] * inv; o1[3] = s[7] * inv;
    *(f32x4*)(attn + (size_t)t * 8)     = o0;
    *(f32x4*)(attn + (size_t)t * 8 + 4) = o1;
}

// ---------------------------------------------------------------------------
// Fused apply kernel v6 = v4 body + i-split.  blockIdx.y = ih selects i-half
// [ih*512, ih*512+512) -> 8 supersteps; OH-partial written to OH0/OH1 and
// summed for free in the Wo GEMM via concat-K ([OH0|OH1] @ [Wo;Wo]).
// Grid (512, 2) doubles resident blocks/CU (the occupancy lever: all apply
// variants measured 44% because grid=512 capped 2 blocks/CU).
// ---------------------------------------------------------------------------
__global__ __launch_bounds__(512, 4)
void apply_attn(const float* __restrict__ attn, const float* __restrict__ mv,
                const bf16* __restrict__ Wvt, bf16* __restrict__ OH0,
                bf16* __restrict__ OH1)
{
    __shared__ bf16 Wl[16 * 1024];     // 32KB [b][h][64i] swz ^(((b^h)&7)<<4)

    const int tid  = threadIdx.x;
    const int wave = tid >> 6, lane = tid & 63;
    const int lm = lane & 15, q = lane >> 4;
    const int b0 = blockIdx.x * 16;
    const int ib = blockIdx.y * 512;   // i-half base
    const int h0 = wave * 2;

    // ---- attn B-frag variants: afv[lb][mt] nonzero only where q==mt
    bf16x8 afv[2][4];
#pragma unroll
    for (int lb = 0; lb < 2; lb++) {
        const float* ap = attn + (size_t)(b0 + wave * 2 + lb) * 128 + lm * 8;
        const float4 x = *(const float4*)(ap);
        const float4 y = *(const float4*)(ap + 4);
        bf16 a8[8];
        a8[0] = (bf16)x.x; a8[1] = (bf16)x.y; a8[2] = (bf16)x.z; a8[3] = (bf16)x.w;
        a8[4] = (bf16)y.x; a8[5] = (bf16)y.y; a8[6] = (bf16)y.z; a8[7] = (bf16)y.w;
#pragma unroll
        for (int mt = 0; mt < 4; mt++) {
            bf16x8 t;
#pragma unroll
            for (int j = 0; j < 8; j++) t[j] = (q == mt) ? a8[j] : (bf16)0.f;
            afv[lb][mt] = t;
        }
    }

    f32x4 oacc[2][4];
#pragma unroll
    for (int i = 0; i < 2; i++)
#pragma unroll
        for (int j = 0; j < 4; j++)
#pragma unroll
            for (int r = 0; r < 4; r++) oacc[i][j][r] = 0.f;

    for (int sp = 0; sp < 8; ++sp) {
        const int i0 = ib + sp * 64;

        // ---- mv A-frags: per row, 8 dense 256B-coalesced dword loads + cvt
        bf16x8 avf[2];
#pragma unroll
        for (int lb = 0; lb < 2; lb++) {
            const float* mp = mv + (size_t)(b0 + wave * 2 + lb) * 8192 + i0 + q * 16 + lm;
            float v[8];
#pragma unroll
            for (int k = 0; k < 8; k++) v[k] = mp[k * 1024];
            bf16x8 t;
#pragma unroll
            for (int k = 0; k < 8; k++) t[k] = (bf16)v[k];
            avf[lb] = t;
        }

        // ---- issue Wvt it=0 batch (L2; lands under Wm-gen + barrier)
        bf16x8 wb[2][4];
#pragma unroll
        for (int hh = 0; hh < 2; hh++) {
            const int h = h0 + hh;
#pragma unroll
            for (int dt = 0; dt < 4; dt++)
                wb[hh][dt] = *(const bf16x8*)(Wvt + (size_t)(h * 64 + dt * 16 + lm) * 1024 + i0 + q * 8);
        }

        // ---- Wm-gen: one dense A-frag x 4 B-variants -> 4 C tiles -> Wl
#pragma unroll
        for (int lb = 0; lb < 2; lb++) {
            const int bb = wave * 2 + lb;
#pragma unroll
            for (int mt = 0; mt < 4; mt++) {
                f32x4 c;
                c[0] = 0.f; c[1] = 0.f; c[2] = 0.f; c[3] = 0.f;
                c = __builtin_amdgcn_mfma_f32_16x16x32_bf16(avf[lb], afv[lb][mt], c, 0, 0, 0);
                bf16x4 o;
                o[0] = (bf16)c[0]; o[1] = (bf16)c[1]; o[2] = (bf16)c[2]; o[3] = (bf16)c[3];
                *(bf16x4*)((char*)Wl + ((((bb * 16 + lm) * 64 + mt * 16 + q * 4) * 2)
                                        ^ (((bb ^ lm) & 7) << 4))) = o;
            }
        }
        block_barrier();   // Wl ready (lgkm only; vmem stays in flight)

        // ---- OH it=0 (consumes wb batch 0)
#pragma unroll
        for (int hh = 0; hh < 2; hh++) {
            const int h = h0 + hh;
            const bf16x8 wa = *(const bf16x8*)((char*)Wl +
                ((((lm * 16 + h) * 64 + q * 8) * 2) ^ (((lm ^ h) & 7) << 4)));
#pragma unroll
            for (int dt = 0; dt < 4; dt++)
                oacc[hh][dt] = __builtin_amdgcn_mfma_f32_16x16x32_bf16(wa, wb[hh][dt], oacc[hh][dt], 0, 0, 0);
        }
        // ---- Wvt it=1 batch + OH it=1
#pragma unroll
        for (int hh = 0; hh < 2; hh++) {
            const int h = h0 + hh;
#pragma unroll
            for (int dt = 0; dt < 4; dt++)
                wb[hh][dt] = *(const bf16x8*)(Wvt + (size_t)(h * 64 + dt * 16 + lm) * 1024 + i0 + 32 + q * 8);
        }
#pragma unroll
        for (int hh = 0; hh < 2; hh++) {
            const int h = h0 + hh;
            const bf16x8 wa = *(const bf16x8*)((char*)Wl +
                ((((lm * 16 + h) * 64 + 32 + q * 8) * 2) ^ (((lm ^ h) & 7) << 4)));
#pragma unroll
            for (int dt = 0; dt < 4; dt++)
                oacc[hh][dt] = __builtin_amdgcn_mfma_f32_16x16x32_bf16(wa, wb[hh][dt], oacc[hh][dt], 0, 0, 0);
        }
        block_barrier();   // Wl consumed; safe to overwrite next superstep
    }

    // store OH partial (rows b = q*4+r, cols h*64 + dt*16 + lm)
    bf16* OHp = blockIdx.y ? OH1 : OH0;
#pragma unroll
    for (int hh = 0; hh < 2; hh++) {
        const int h = h0 + hh;
#pragma unroll
        for (int dt = 0; dt < 4; dt++) {
#pragma unroll
            for (int r = 0; r < 4; r++)
                OHp[(size_t)(b0 + q * 4 + r) * 1024 + h * 64 + dt * 16 + lm] = (bf16)oacc[hh][dt][r];
        }
    }
}

// ---------------------------------------------------------------------------
// sigmoid gate + residual + LayerNorm. One block per row.
// ---------------------------------------------------------------------------
__global__ __launch_bounds__(256)
void gate_ln_kernel(const float* __restrict__ hs, const float* __restrict__ mo,
                    const float* __restrict__ z,  const float* __restrict__ bg,
                    const float* __restrict__ lng, const float* __restrict__ lnb,
                    float* __restrict__ out)
{
    __shared__ float s1[4], s2[4];
    const int tid = threadIdx.x;
    const size_t base = (size_t)blockIdx.x * 1024 + tid * 4;

    const float4 h4 = *(const float4*)&hs[base];
    const float4 m4 = *(const float4*)&mo[base];
    const float4 z4 = *(const float4*)&z[base];
    const float4 bg4 = *(const float4*)&bg[tid * 4];

    float a[4];
    {
        const float g0 = 1.f / (1.f + __expf(-(z4.x + bg4.x)));
        const float g1 = 1.f / (1.f + __expf(-(z4.y + bg4.y)));
        const float g2 = 1.f / (1.f + __expf(-(z4.z + bg4.z)));
        const float g3 = 1.f / (1.f + __expf(-(z4.w + bg4.w)));
        a[0] = h4.x + g0 * m4.x;
        a[1] = h4.y + g1 * m4.y;
        a[2] = h4.z + g2 * m4.z;
        a[3] = h4.w + g3 * m4.w;
    }
    float sum = a[0] + a[1] + a[2] + a[3];
    float sq  = a[0]*a[0] + a[1]*a[1] + a[2]*a[2] + a[3]*a[3];
#pragma unroll
    for (int off = 32; off >= 1; off >>= 1) {
        sum += __shfl_xor(sum, off);
        sq  += __shfl_xor(sq,  off);
    }
    const int wave = tid >> 6;
    if ((tid & 63) == 0) { s1[wave] = sum; s2[wave] = sq; }
    __syncthreads();
    const float mean = (s1[0] + s1[1] + s1[2] + s1[3]) * (1.f / 1024.f);
    const float var  = (s2[0] + s2[1] + s2[2] + s2[3]) * (1.f / 1024.f) - mean * mean;
    const float inv  = rsqrtf(var + 1e-5f);

    const float4 g4 = *(const float4*)&lng[tid * 4];
    const float4 b4 = *(const float4*)&lnb[tid * 4];
    float4 o;
    o.x = (a[0] - mean) * inv * g4.x + b4.x;
    o.y = (a[1] - mean) * inv * g4.y + b4.y;
    o.z = (a[2] - mean) * inv * g4.z + b4.z;
    o.w = (a[3] - mean) * inv * g4.w + b4.w;
    *(float4*)&out[base] = o;
}

// ---------------------------------------------------------------------------
extern "C" void kernel_launch(void* const* d_in, const int* in_sizes, int n_in,
                              void* d_out, int out_size, void* d_ws, size_t ws_size,
                              hipStream_t stream)
{
    const float* hs  = (const float*)d_in[0];
    const float* mk  = (const float*)d_in[1];
    const float* mv  = (const float*)d_in[2];
    const float* Wq  = (const float*)d_in[3];
    const float* Wk  = (const float*)d_in[4];
    const float* Wv  = (const float*)d_in[5];
    const float* Wo  = (const float*)d_in[6];
    const float* Wg  = (const float*)d_in[7];
    const float* bg  = (const float*)d_in[8];
    const float* lng = (const float*)d_in[9];
    const float* lnb = (const float*)d_in[10];
    float* out = (float*)d_out;

    const int B = 8192;
    const dim3 tb(256);

    char* ws = (char*)d_ws;
    bf16*  Wq_t = (bf16*)(ws);                        // 2 MB  (1024x1024, N x K)
    bf16*  Wv_t = (bf16*)(ws + ((size_t)2  << 20));   // 2 MB
    bf16*  Wg_t = (bf16*)(ws + ((size_t)6  << 20));   // 4 MB  (1024x2048)
    bf16*  Wk_b = (bf16*)(ws + ((size_t)10 << 20));   // 2 MB  (1024x1024, NOT transposed)
    bf16*  hs_b = (bf16*)(ws + ((size_t)12 << 20));   // 16 MB (8192x1024)
    bf16*  Qb   = (bf16*)(ws + ((size_t)28 << 20));   // 16 MB
    bf16*  OH0  = (bf16*)(ws + ((size_t)44 << 20));   // 16 MB
    float* Mo   = (float*)(ws + ((size_t)60 << 20));  // 32 MB
    bf16*  Mo_b = (bf16*)(ws + ((size_t)92 << 20));   // 16 MB
    float* Zb   = (float*)(ws + ((size_t)108 << 20)); // 32 MB
    float* At   = (float*)(ws + ((size_t)140 << 20)); // 4 MB  (8192x16x8 fp32)
    float* Atp  = (float*)(ws + ((size_t)144 << 20)); // 64 MB (16 x 8192x16x8 fp32)
    bf16*  Wo_t2= (bf16*)(ws + ((size_t)208 << 20));  // 4 MB  (1024 x 2048, [Wo;Wo])
    bf16*  OH1  = (bf16*)(ws + ((size_t)212 << 20));  // 16 MB

    transpose_cvt<<<dim3(32, 32), tb, 0, stream>>>(Wq, Wq_t, 1024, 1024);
    transpose_cvt<<<dim3(32, 32), tb, 0, stream>>>(Wv, Wv_t, 1024, 1024);
    // duplicated-K Wo: Wo_t2[n, k] = Wo[k%1024, n]  (two passes)
    transpose_cvt<<<dim3(32, 32), tb, 0, stream>>>(Wo, Wo_t2,        2048, 1024);
    transpose_cvt<<<dim3(32, 32), tb, 0, stream>>>(Wo, Wo_t2 + 1024, 2048, 1024);
    transpose_cvt<<<dim3(32, 64), tb, 0, stream>>>(Wg, Wg_t, 2048, 1024);
    cvt_bf16<<<dim3(1024 * 1024 / 8 / 256), tb, 0, stream>>>(Wk, Wk_b, 1024 * 1024 / 8);
    cvt_bf16<<<dim3(B * 1024 / 8 / 256), tb, 0, stream>>>(hs, hs_b, B * 1024 / 8);

    // Q = hs @ Wq -> bf16 (B x 1024)
    gemm_a97<false><<<dim3(8, 64, 1), tb, 0, stream>>>(
        hs_b, nullptr, Wq_t, nullptr, Qb,
        1024, 1024, 1024, 0, 1024, 1024, 0, 0, 0);
    // weight-stationary partial scores (16 i-chunks x 64 b-groups)
    score_attn_part<<<dim3(64, 16), dim3(512), 0, stream>>>(Qb, Wk_b, mk, Atp);
    // reduce chunks + softmax -> attn
    reduce_softmax<<<dim3(512), tb, 0, stream>>>(Atp, At);
    // fused: W_mix-gen + V-proj over i-halves -> OH0/OH1 partials
    apply_attn<<<dim3(B / 16, 2), dim3(512), 0, stream>>>(At, mv, Wv_t, OH0, OH1);
    // memory_out = OH0 @ Wo + OH1 @ Wo  (concat-K) -> fp32 Mo + bf16 Mo_b
    gemm_a97<true><<<dim3(8, 64, 1), tb, 0, stream>>>(
        OH0, OH1, Wo_t2, Mo, Mo_b,
        2048, 1024, 1024, 1024, 2048, 1024, 0, 0, 0);
    // z = [hs, Mo] @ Wg -> fp32
    gemm_a97<true><<<dim3(8, 64, 1), tb, 0, stream>>>(
        hs_b, Mo_b, Wg_t, Zb, nullptr,
        2048, 1024, 1024, 1024, 2048, 1024, 0, 0, 0);
    // gate + residual + LayerNorm
    gate_ln_kernel<<<dim3(B), tb, 0, stream>>>(
        hs, Mo, Zb, bg, lng, lnb, out);
}

// Round 8
// 505.580 us; speedup vs baseline: 1.2950x; 1.0968x over previous
//
#include <hip/hip_runtime.h>
#include <hip/hip_bf16.h>

typedef __bf16 bf16;
typedef __bf16 bf16x8 __attribute__((ext_vector_type(8)));
typedef __bf16 bf16x4 __attribute__((ext_vector_type(4)));
typedef float  f32x4  __attribute__((ext_vector_type(4)));

// ---------------------------------------------------------------------------
// raw barrier: flush LDS ops (lgkmcnt), DO NOT drain vmcnt — in-flight global
// loads survive the barrier.  __syncthreads() would insert vmcnt(0) and kill
// the register prefetch issued just before it.
// ---------------------------------------------------------------------------
__device__ __forceinline__ void block_barrier()
{
    asm volatile("s_waitcnt lgkmcnt(0)\n\ts_barrier" ::: "memory");
}

// ---------------------------------------------------------------------------
// async global->LDS 16B per lane: LDS dst = wave-uniform base + lane*16B
// ---------------------------------------------------------------------------
#if defined(__has_builtin)
#if __has_builtin(__builtin_amdgcn_global_load_lds)
#define HAS_GLD 1
#endif
#endif
#ifndef HAS_GLD
#define HAS_GLD 0
#endif

__device__ __forceinline__ void gld_lds16(const bf16* g, bf16* lds_base)
{
#if HAS_GLD
    __builtin_amdgcn_global_load_lds(
        (const __attribute__((address_space(1))) void*)g,
        (__attribute__((address_space(3))) void*)lds_base, 16, 0, 0);
#else
    *(bf16x8*)(lds_base + (threadIdx.x & 63) * 8) = *(const bf16x8*)g;
#endif
}

// ---------------------------------------------------------------------------
// Weight transpose + fp32->bf16: src (K,N) row-major -> dst (N,K)
// ---------------------------------------------------------------------------
__global__ __launch_bounds__(256)
void transpose_cvt(const float* __restrict__ src, bf16* __restrict__ dst, int K, int N)
{
    __shared__ float t[32][33];
    const int bx = blockIdx.x, by = blockIdx.y, tid = threadIdx.x;
    const int c = tid & 31, r0 = tid >> 5;
#pragma unroll
    for (int p = 0; p < 4; p++) {
        int r = r0 + p * 8;
        t[r][c] = src[(size_t)(by * 32 + r) * N + bx * 32 + c];
    }
    __syncthreads();
#pragma unroll
    for (int p = 0; p < 4; p++) {
        int r = r0 + p * 8;
        dst[(size_t)(bx * 32 + r) * K + by * 32 + c] = (bf16)t[c][r];
    }
}

// ---------------------------------------------------------------------------
// plain fp32 -> bf16 convert, 8 elems/thread
// ---------------------------------------------------------------------------
__global__ __launch_bounds__(256)
void cvt_bf16(const float* __restrict__ src, bf16* __restrict__ dst, int n8)
{
    const int i = blockIdx.x * 256 + threadIdx.x;
    if (i >= n8) return;
    const float4* s = (const float4*)(src + (size_t)i * 8);
    float4 a = s[0], b = s[1];
    bf16x8 o;
    o[0] = (bf16)a.x; o[1] = (bf16)a.y; o[2] = (bf16)a.z; o[3] = (bf16)a.w;
    o[4] = (bf16)b.x; o[5] = (bf16)b.y; o[6] = (bf16)b.z; o[7] = (bf16)b.w;
    *(bf16x8*)(dst + (size_t)i * 8) = o;
}

// ---------------------------------------------------------------------------
// m97-style GEMM: C = A @ B.  A bf16 (rows via ldA), Bt bf16 (N x K, ldB).
// 128x128 tile, BK=32, global_load_lds staging, XCD swizzle (gridDim.x==8).
// Optional A2 for concat-K (gate).
// ---------------------------------------------------------------------------
template<bool TWOA>
__global__ __launch_bounds__(256)
void gemm_a97(const bf16* __restrict__ A1, const bf16* __restrict__ A2,
              const bf16* __restrict__ Bt, float* __restrict__ Cf,
              bf16* __restrict__ Cb, int Kloop, int Ksplit,
              int ldA, int ldA2, int ldB, int ldC,
              long az, long bz, long cz)
{
    __shared__ bf16 Al[128 * 32];
    __shared__ bf16 Bl[128 * 32];

    const int z = blockIdx.z;
    A1 += (size_t)z * az;
    Bt += (size_t)z * bz;
    if (Cf) Cf += (size_t)z * cz;
    if (Cb) Cb += (size_t)z * cz;

    int bx, by;
    {
        const int gy = gridDim.y;
        const int flat = blockIdx.y * gridDim.x + blockIdx.x;
        if ((gy & 7) == 0 && gridDim.x == 8) {
            const int xcd = flat & 7, slot = flat >> 3, mpx = gy >> 3;
            by = xcd * mpx + (slot >> 3);
            bx = slot & 7;
        } else { bx = blockIdx.x; by = blockIdx.y; }
    }

    const int tid = threadIdx.x;
    const int wave = tid >> 6, lane = tid & 63;
    const int m0 = by * 128, n0 = bx * 128;
    const int rl = lane >> 2;
    const int kc = (lane & 3) * 8;
    const int wm = wave >> 1, wn = wave & 1, lm = lane & 15, quad = lane >> 4;

    f32x4 acc[4][4];
#pragma unroll
    for (int i = 0; i < 4; i++)
#pragma unroll
        for (int j = 0; j < 4; j++)
#pragma unroll
            for (int r = 0; r < 4; r++) acc[i][j][r] = 0.f;

    for (int k0 = 0; k0 < Kloop; k0 += 32) {
        const bf16* Ab; int kof, ld;
        if (TWOA && k0 >= Ksplit) { Ab = A2; kof = k0 - Ksplit; ld = ldA2; }
        else                      { Ab = A1; kof = k0;          ld = ldA;  }
        const int r0 = wave * 32 + rl, r1 = r0 + 16;
        gld_lds16(Ab + (size_t)(m0 + r0) * ld + kof + kc, Al + (wave * 32) * 32);
        gld_lds16(Ab + (size_t)(m0 + r1) * ld + kof + kc, Al + (wave * 32 + 16) * 32);
        gld_lds16(Bt + (size_t)(n0 + r0) * ldB + k0 + kc, Bl + (wave * 32) * 32);
        gld_lds16(Bt + (size_t)(n0 + r1) * ldB + k0 + kc, Bl + (wave * 32 + 16) * 32);
        __syncthreads();

        bf16x8 af[4], bfr[4];
#pragma unroll
        for (int i = 0; i < 4; i++)
            af[i] = *(const bf16x8*)&Al[(wm * 64 + i * 16 + lm) * 32 + quad * 8];
#pragma unroll
        for (int j = 0; j < 4; j++)
            bfr[j] = *(const bf16x8*)&Bl[(wn * 64 + j * 16 + lm) * 32 + quad * 8];
#pragma unroll
        for (int i = 0; i < 4; i++)
#pragma unroll
            for (int j = 0; j < 4; j++)
                acc[i][j] = __builtin_amdgcn_mfma_f32_16x16x32_bf16(af[i], bfr[j], acc[i][j], 0, 0, 0);
        __syncthreads();
    }

#pragma unroll
    for (int i = 0; i < 4; i++) {
        const int rbase = m0 + wm * 64 + i * 16 + quad * 4;
#pragma unroll
        for (int j = 0; j < 4; j++) {
            const int c = n0 + wn * 64 + j * 16 + lm;
#pragma unroll
            for (int r = 0; r < 4; r++) {
                const float v = acc[i][j][r];
                const size_t idx = (size_t)(rbase + r) * ldC + c;
                if (Cf) Cf[idx] = v;
                if (Cb) Cb[idx] = (bf16)v;
            }
        }
    }
}

// ---------------------------------------------------------------------------
// Weight-stationary partial-score kernel (unchanged from R4, verified).
// ---------------------------------------------------------------------------
__global__ __launch_bounds__(512, 4)
void score_attn_part(const bf16* __restrict__ Qb, const bf16* __restrict__ Wkb,
                     const float* __restrict__ mk, float* __restrict__ part)
{
    __shared__ bf16 Ul[16 * 1024];   // 32KB [b16][h16][64i] swz ^(((b^h)&7)<<4)

    const int tid  = threadIdx.x;
    const int wave = tid >> 6, lane = tid & 63;
    const int lm = lane & 15, q = lane >> 4;
    const int g  = blockIdx.x;       // b-group: rows [g*128, g*128+128)
    const int c  = blockIdx.y;       // i-chunk: i in [c*64, c*64+64)
    const int i0 = c * 64;
    const int h0 = wave * 2;

    // ---- weight-stationary Wk fragments (16 bf16x8 = 64 VGPR), loaded once
    bf16x8 wk[2][4][2];
#pragma unroll
    for (int hh = 0; hh < 2; hh++)
#pragma unroll
        for (int mt = 0; mt < 4; mt++) {
            const bf16* wp = Wkb + (size_t)(i0 + mt * 16 + lm) * 1024 + (h0 + hh) * 64 + q * 8;
            wk[hh][mt][0] = *(const bf16x8*)(wp);
            wk[hh][mt][1] = *(const bf16x8*)(wp + 32);
        }

    float* pbase = part + ((size_t)c << 20);   // c * 8192*128

    for (int t = 0; t < 8; ++t) {
        const int b0 = g * 128 + t * 16;

        // ---- Q B-frags for this b-tile (rows = b, K = d)
        bf16x8 qf[2][2];
#pragma unroll
        for (int hh = 0; hh < 2; hh++) {
            const bf16* qp = Qb + (size_t)(b0 + lm) * 1024 + (h0 + hh) * 64 + q * 8;
            qf[hh][0] = *(const bf16x8*)(qp);
            qf[hh][1] = *(const bf16x8*)(qp + 32);
        }

        // ---- U-gen: C[i][b] tiles -> Ul
#pragma unroll
        for (int hh = 0; hh < 2; hh++) {
            const int h = h0 + hh;
#pragma unroll
            for (int mt = 0; mt < 4; mt++) {
                f32x4 c4;
                c4[0] = 0.f; c4[1] = 0.f; c4[2] = 0.f; c4[3] = 0.f;
                c4 = __builtin_amdgcn_mfma_f32_16x16x32_bf16(wk[hh][mt][0], qf[hh][0], c4, 0, 0, 0);
                c4 = __builtin_amdgcn_mfma_f32_16x16x32_bf16(wk[hh][mt][1], qf[hh][1], c4, 0, 0, 0);
                bf16x4 o;
                o[0] = (bf16)c4[0]; o[1] = (bf16)c4[1]; o[2] = (bf16)c4[2]; o[3] = (bf16)c4[3];
                *(bf16x4*)((char*)Ul + ((((lm * 16 + h) * 64 + mt * 16 + q * 4) * 2)
                                        ^ (((lm ^ h) & 7) << 4))) = o;
            }
        }
        __syncthreads();

        // ---- score: wave's 2 rows; mk B-frags direct from global (+cvt)
#pragma unroll
        for (int lb = 0; lb < 2; lb++) {
            const int bb = wave * 2 + lb;
            const float* mp = mk + (size_t)(b0 + bb) * 8192 + (lm & 7) * 1024 + i0 + q * 8;
            const f32x4 a0 = *(const f32x4*)(mp);
            const f32x4 a1 = *(const f32x4*)(mp + 4);
            const f32x4 b0v = *(const f32x4*)(mp + 32);
            const f32x4 b1v = *(const f32x4*)(mp + 36);
            bf16x8 m0, m1;
            m0[0] = (bf16)a0[0]; m0[1] = (bf16)a0[1]; m0[2] = (bf16)a0[2]; m0[3] = (bf16)a0[3];
            m0[4] = (bf16)a1[0]; m0[5] = (bf16)a1[1]; m0[6] = (bf16)a1[2]; m0[7] = (bf16)a1[3];
            m1[0] = (bf16)b0v[0]; m1[1] = (bf16)b0v[1]; m1[2] = (bf16)b0v[2]; m1[3] = (bf16)b0v[3];
            m1[4] = (bf16)b1v[0]; m1[5] = (bf16)b1v[1]; m1[6] = (bf16)b1v[2]; m1[7] = (bf16)b1v[3];

            const bf16x8 ua0 = *(const bf16x8*)((char*)Ul +
                ((((bb * 16 + lm) * 64 + q * 8) * 2) ^ (((bb ^ lm) & 7) << 4)));
            const bf16x8 ua1 = *(const bf16x8*)((char*)Ul +
                ((((bb * 16 + lm) * 64 + 32 + q * 8) * 2) ^ (((bb ^ lm) & 7) << 4)));

            f32x4 s4;
            s4[0] = 0.f; s4[1] = 0.f; s4[2] = 0.f; s4[3] = 0.f;
            s4 = __builtin_amdgcn_mfma_f32_16x16x32_bf16(ua0, m0, s4, 0, 0, 0);
            s4 = __builtin_amdgcn_mfma_f32_16x16x32_bf16(ua1, m1, s4, 0, 0, 0);

            // C[h=q*4+r][k=lm&7] for row b0+bb; lm>=8 is a duplicate
            if (lm < 8) {
                float* pp = pbase + (size_t)(b0 + bb) * 128 + lm;
#pragma unroll
                for (int r = 0; r < 4; r++) pp[(q * 4 + r) * 8] = s4[r];
            }
        }
        __syncthreads();
    }
}

// ---------------------------------------------------------------------------
// reduce 16 i-chunk partials + softmax over k -> attn (B x 16 x 8 fp32)
// ---------------------------------------------------------------------------
__global__ __launch_bounds__(256)
void reduce_softmax(const float* __restrict__ part, float* __restrict__ attn)
{
    const int t = blockIdx.x * 256 + threadIdx.x;   // (b*16 + h)
    const float* p = part + (size_t)t * 8;
    float s[8] = {0.f, 0.f, 0.f, 0.f, 0.f, 0.f, 0.f, 0.f};
#pragma unroll
    for (int c = 0; c < 16; ++c) {
        const f32x4 a = *(const f32x4*)(p + ((size_t)c << 20));
        const f32x4 b = *(const f32x4*)(p + ((size_t)c << 20) + 4);
        s[0] += a[0]; s[1] += a[1]; s[2] += a[2]; s[3] += a[3];
        s[4] += b[0]; s[5] += b[1]; s[6] += b[2]; s[7] += b[3];
    }
#pragma unroll
    for (int k = 0; k < 8; k++) s[k] *= 0.125f;     // DH^-0.5
    float mx = s[0];
#pragma unroll
    for (int k = 1; k < 8; k++) mx = fmaxf(mx, s[k]);
    float den = 0.f;
#pragma unroll
    for (int k = 0; k < 8; k++) { s[k] = __expf(s[k] - mx); den += s[k]; }
    const float inv = 1.f / den;
    f32x4 o0, o1;
    o0[0] = s[0] * inv; o0[1] = s[1] * inv; o0[2] = s[2] * inv; o0[3] = s[3] * inv;
    o1[0] = s[4] * inv; o1[1] = s[5] * inv; o1[2] = s[6] * inv; o1[3] = s[7] * inv;
    *(f32x4*)(attn + (size_t)t * 8)     = o0;
    *(f32x4*)(attn + (size_t)t * 8 + 4) = o1;
}

// ---------------------------------------------------------------------------
// Fused apply kernel v7 = R2/R4 body (Vl double-buffer, 183µs verified) with
// ONE change: the two __syncthreads() -> lgkm-only barriers.  The mv register
// prefetch issued before barrier #1 now survives both barriers and lands
// under Wm-gen + OH instead of being drained by vmcnt(0) at the barrier.
// ---------------------------------------------------------------------------
__global__ __launch_bounds__(512, 4)
void apply_attn(const float* __restrict__ attn, const float* __restrict__ mv,
                const bf16* __restrict__ Wvt, bf16* __restrict__ OH)
{
    __shared__ bf16 Vl[2][8192];       // 2x16KB [b][i][8k] swz ^(((i>>2)&7)<<4)
    __shared__ bf16 Wl[16 * 1024];     // 32KB [b][h][64i] swz ^(((b^h)&7)<<4)

    const int tid  = threadIdx.x;
    const int wave = tid >> 6, lane = tid & 63;
    const int lm = lane & 15, q = lane >> 4;
    const int b0 = blockIdx.x * 16;
    const int h0 = wave * 2;

    // attn B-frags for wave's 2 rows: rows = h, K = k (quads 1-3 zero pad)
    bf16x8 af[2];
#pragma unroll
    for (int lb = 0; lb < 2; lb++) {
        bf16x8 t;
#pragma unroll
        for (int j = 0; j < 8; j++) t[j] = (bf16)0.f;
        if (q == 0) {
            const float* ap = attn + (size_t)(b0 + wave * 2 + lb) * 128 + lm * 8;
            const float4 x = *(const float4*)(ap);
            const float4 y = *(const float4*)(ap + 4);
            t[0] = (bf16)x.x; t[1] = (bf16)x.y; t[2] = (bf16)x.z; t[3] = (bf16)x.w;
            t[4] = (bf16)y.x; t[5] = (bf16)y.y; t[6] = (bf16)y.z; t[7] = (bf16)y.w;
        }
        af[lb] = t;
    }

    f32x4 oacc[2][4];
#pragma unroll
    for (int i = 0; i < 2; i++)
#pragma unroll
        for (int j = 0; j < 4; j++)
#pragma unroll
            for (int r = 0; r < 4; r++) oacc[i][j][r] = 0.f;

    // mv staging mapping: thread -> (b = tid>>5, i = (tid&15)*4..+3, 4 k's)
    const int bb_s = tid >> 5;             // 0..15
    const int i4   = (tid & 15) * 4;
    const int kh   = ((tid >> 4) & 1) * 4; // k-half: 0 or 4
    const float* mvbase = mv + (size_t)(b0 + bb_s) * 8192;

    f32x4 pre[4];
#pragma unroll
    for (int k = 0; k < 4; k++)
        pre[k] = *(const f32x4*)(mvbase + (kh + k) * 1024 + i4);
#pragma unroll
    for (int jj = 0; jj < 4; jj++) {
        const int i = i4 + jj;
        bf16x4 o;
        o[0] = (bf16)pre[0][jj]; o[1] = (bf16)pre[1][jj];
        o[2] = (bf16)pre[2][jj]; o[3] = (bf16)pre[3][jj];
        *(bf16x4*)((char*)&Vl[0][0] + ((((bb_s * 64 + i) * 8 + kh) * 2)
                                       ^ (((i >> 2) & 7) << 4))) = o;
    }

    for (int sp = 0; sp < 16; ++sp) {
        const int i0 = sp * 64;
        const int ni = (sp == 15) ? 0 : i0 + 64;

        // prefetch next mv slice (stays in flight across the lgkm barriers)
#pragma unroll
        for (int k = 0; k < 4; k++)
            pre[k] = *(const f32x4*)(mvbase + (kh + k) * 1024 + ni + i4);

        block_barrier();   // Vl[sp&1] ds_writes visible; vmem NOT drained

        // Wm-gen: wave's 2 rows, C[i][h] 16x16 tiles -> Wl (ds ops only)
#pragma unroll
        for (int lb = 0; lb < 2; lb++) {
            const int bb = wave * 2 + lb;
#pragma unroll
            for (int mt = 0; mt < 4; mt++) {
                bf16x8 a;
#pragma unroll
                for (int j = 0; j < 8; j++) a[j] = (bf16)0.f;
                if (q == 0) {
                    const int i = mt * 16 + lm;
                    a = *(const bf16x8*)((char*)&Vl[sp & 1][0] +
                        ((((bb * 64 + i) * 8) * 2) ^ (((i >> 2) & 7) << 4)));
                }
                f32x4 c;
                c[0] = 0.f; c[1] = 0.f; c[2] = 0.f; c[3] = 0.f;
                c = __builtin_amdgcn_mfma_f32_16x16x32_bf16(a, af[lb], c, 0, 0, 0);
                bf16x4 o;
                o[0] = (bf16)c[0]; o[1] = (bf16)c[1]; o[2] = (bf16)c[2]; o[3] = (bf16)c[3];
                *(bf16x4*)((char*)Wl + ((((bb * 16 + lm) * 64 + mt * 16 + q * 4) * 2)
                                        ^ (((bb ^ lm) & 7) << 4))) = o;
            }
        }
        block_barrier();   // Wl ready; prefetch still in flight

        // OH accumulate: wave's 2 heads vs L2-resident Wv_t
#pragma unroll
        for (int hh = 0; hh < 2; hh++) {
            const int h = h0 + hh;
#pragma unroll
            for (int it = 0; it < 2; it++) {
                const bf16x8 wa = *(const bf16x8*)((char*)Wl +
                    ((((lm * 16 + h) * 64 + it * 32 + q * 8) * 2) ^ (((lm ^ h) & 7) << 4)));
                const bf16* wv = Wvt + (size_t)(h * 64 + lm) * 1024 + i0 + it * 32 + q * 8;
#pragma unroll
                for (int dt = 0; dt < 4; dt++) {
                    const bf16x8 wb = *(const bf16x8*)(wv + (size_t)dt * 16 * 1024);
                    oacc[hh][dt] = __builtin_amdgcn_mfma_f32_16x16x32_bf16(wa, wb, oacc[hh][dt], 0, 0, 0);
                }
            }
        }

        // stage next mv slice (pre has had Wm-gen + OH as latency cover)
#pragma unroll
        for (int jj = 0; jj < 4; jj++) {
            const int i = i4 + jj;
            bf16x4 o;
            o[0] = (bf16)pre[0][jj]; o[1] = (bf16)pre[1][jj];
            o[2] = (bf16)pre[2][jj]; o[3] = (bf16)pre[3][jj];
            *(bf16x4*)((char*)&Vl[(sp + 1) & 1][0] + ((((bb_s * 64 + i) * 8 + kh) * 2)
                                                      ^ (((i >> 2) & 7) << 4))) = o;
        }
    }

    // store OH (rows b = q*4+r, cols h*64 + dt*16 + lm)
#pragma unroll
    for (int hh = 0; hh < 2; hh++) {
        const int h = h0 + hh;
#pragma unroll
        for (int dt = 0; dt < 4; dt++) {
#pragma unroll
            for (int r = 0; r < 4; r++)
                OH[(size_t)(b0 + q * 4 + r) * 1024 + h * 64 + dt * 16 + lm] = (bf16)oacc[hh][dt][r];
        }
    }
}

// ---------------------------------------------------------------------------
// sigmoid gate + residual + LayerNorm. One block per row.
// ---------------------------------------------------------------------------
__global__ __launch_bounds__(256)
void gate_ln_kernel(const float* __restrict__ hs, const float* __restrict__ mo,
                    const float* __restrict__ z,  const float* __restrict__ bg,
                    const float* __restrict__ lng, const float* __restrict__ lnb,
                    float* __restrict__ out)
{
    __shared__ float s1[4], s2[4];
    const int tid = threadIdx.x;
    const size_t base = (size_t)blockIdx.x * 1024 + tid * 4;

    const float4 h4 = *(const float4*)&hs[base];
    const float4 m4 = *(const float4*)&mo[base];
    const float4 z4 = *(const float4*)&z[base];
    const float4 bg4 = *(const float4*)&bg[tid * 4];

    float a[4];
    {
        const float g0 = 1.f / (1.f + __expf(-(z4.x + bg4.x)));
        const float g1 = 1.f / (1.f + __expf(-(z4.y + bg4.y)));
        const float g2 = 1.f / (1.f + __expf(-(z4.z + bg4.z)));
        const float g3 = 1.f / (1.f + __expf(-(z4.w + bg4.w)));
        a[0] = h4.x + g0 * m4.x;
        a[1] = h4.y + g1 * m4.y;
        a[2] = h4.z + g2 * m4.z;
        a[3] = h4.w + g3 * m4.w;
    }
    float sum = a[0] + a[1] + a[2] + a[3];
    float sq  = a[0]*a[0] + a[1]*a[1] + a[2]*a[2] + a[3]*a[3];
#pragma unroll
    for (int off = 32; off >= 1; off >>= 1) {
        sum += __shfl_xor(sum, off);
        sq  += __shfl_xor(sq,  off);
    }
    const int wave = tid >> 6;
    if ((tid & 63) == 0) { s1[wave] = sum; s2[wave] = sq; }
    __syncthreads();
    const float mean = (s1[0] + s1[1] + s1[2] + s1[3]) * (1.f / 1024.f);
    const float var  = (s2[0] + s2[1] + s2[2] + s2[3]) * (1.f / 1024.f) - mean * mean;
    const float inv  = rsqrtf(var + 1e-5f);

    const float4 g4 = *(const float4*)&lng[tid * 4];
    const float4 b4 = *(const float4*)&lnb[tid * 4];
    float4 o;
    o.x = (a[0] - mean) * inv * g4.x + b4.x;
    o.y = (a[1] - mean) * inv * g4.y + b4.y;
    o.z = (a[2] - mean) * inv * g4.z + b4.z;
    o.w = (a[3] - mean) * inv * g4.w + b4.w;
    *(float4*)&out[base] = o;
}

// ---------------------------------------------------------------------------
extern "C" void kernel_launch(void* const* d_in, const int* in_sizes, int n_in,
                              void* d_out, int out_size, void* d_ws, size_t ws_size,
                              hipStream_t stream)
{
    const float* hs  = (const float*)d_in[0];
    const float* mk  = (const float*)d_in[1];
    const float* mv  = (const float*)d_in[2];
    const float* Wq  = (const float*)d_in[3];
    const float* Wk  = (const float*)d_in[4];
    const float* Wv  = (const float*)d_in[5];
    const float* Wo  = (const float*)d_in[6];
    const float* Wg  = (const float*)d_in[7];
    const float* bg  = (const float*)d_in[8];
    const float* lng = (const float*)d_in[9];
    const float* lnb = (const float*)d_in[10];
    float* out = (float*)d_out;

    const int B = 8192;
    const dim3 tb(256);

    char* ws = (char*)d_ws;
    bf16*  Wq_t = (bf16*)(ws);                        // 2 MB  (1024x1024, N x K)
    bf16*  Wv_t = (bf16*)(ws + ((size_t)2  << 20));   // 2 MB
    bf16*  Wo_t = (bf16*)(ws + ((size_t)4  << 20));   // 2 MB
    bf16*  Wg_t = (bf16*)(ws + ((size_t)6  << 20));   // 4 MB  (1024x2048)
    bf16*  Wk_b = (bf16*)(ws + ((size_t)10 << 20));   // 2 MB  (1024x1024, NOT transposed)
    bf16*  hs_b = (bf16*)(ws + ((size_t)12 << 20));   // 16 MB (8192x1024)
    bf16*  Qb   = (bf16*)(ws + ((size_t)28 << 20));   // 16 MB
    bf16*  OH   = (bf16*)(ws + ((size_t)44 << 20));   // 16 MB
    float* Mo   = (float*)(ws + ((size_t)60 << 20));  // 32 MB
    bf16*  Mo_b = (bf16*)(ws + ((size_t)92 << 20));   // 16 MB
    float* Zb   = (float*)(ws + ((size_t)108 << 20)); // 32 MB
    float* At   = (float*)(ws + ((size_t)140 << 20)); // 4 MB  (8192x16x8 fp32)
    float* Atp  = (float*)(ws + ((size_t)144 << 20)); // 64 MB (16 x 8192x16x8 fp32)

    transpose_cvt<<<dim3(32, 32), tb, 0, stream>>>(Wq, Wq_t, 1024, 1024);
    transpose_cvt<<<dim3(32, 32), tb, 0, stream>>>(Wv, Wv_t, 1024, 1024);
    transpose_cvt<<<dim3(32, 32), tb, 0, stream>>>(Wo, Wo_t, 1024, 1024);
    transpose_cvt<<<dim3(32, 64), tb, 0, stream>>>(Wg, Wg_t, 2048, 1024);
    cvt_bf16<<<dim3(1024 * 1024 / 8 / 256), tb, 0, stream>>>(Wk, Wk_b, 1024 * 1024 / 8);
    cvt_bf16<<<dim3(B * 1024 / 8 / 256), tb, 0, stream>>>(hs, hs_b, B * 1024 / 8);

    // Q = hs @ Wq -> bf16 (B x 1024)
    gemm_a97<false><<<dim3(8, 64, 1), tb, 0, stream>>>(
        hs_b, nullptr, Wq_t, nullptr, Qb,
        1024, 1024, 1024, 0, 1024, 1024, 0, 0, 0);
    // weight-stationary partial scores (16 i-chunks x 64 b-groups)
    score_attn_part<<<dim3(64, 16), dim3(512), 0, stream>>>(Qb, Wk_b, mk, Atp);
    // reduce chunks + softmax -> attn
    reduce_softmax<<<dim3(512), tb, 0, stream>>>(Atp, At);
    // fused: W_mix-gen + V-proj -> OH (B x 1024 bf16)
    apply_attn<<<dim3(B / 16), dim3(512), 0, stream>>>(At, mv, Wv_t, OH);
    // memory_out = OH @ Wo -> fp32 Mo + bf16 Mo_b
    gemm_a97<false><<<dim3(8, 64, 1), tb, 0, stream>>>(
        OH, nullptr, Wo_t, Mo, Mo_b,
        1024, 1024, 1024, 0, 1024, 1024, 0, 0, 0);
    // z = [hs, Mo] @ Wg -> fp32
    gemm_a97<true><<<dim3(8, 64, 1), tb, 0, stream>>>(
        hs_b, Mo_b, Wg_t, Zb, nullptr,
        2048, 1024, 1024, 1024, 2048, 1024, 0, 0, 0);
    // gate + residual + LayerNorm
    gate_ln_kernel<<<dim3(B), tb, 0, stream>>>(
        hs, Mo, Zb, bg, lng, lnb, out);
}

// Round 9
// 485.537 us; speedup vs baseline: 1.3484x; 1.0413x over previous
//
#include <hip/hip_runtime.h>
#include <hip/hip_bf16.h>

typedef __bf16 bf16;
typedef __bf16 bf16x8 __attribute__((ext_vector_type(8)));
typedef __bf16 bf16x4 __attribute__((ext_vector_type(4)));
typedef float  f32x4  __attribute__((ext_vector_type(4)));

// ---------------------------------------------------------------------------
// raw barrier: flush LDS ops (lgkmcnt), DO NOT drain vmcnt — in-flight global
// loads / global_load_lds survive the barrier.
// ---------------------------------------------------------------------------
__device__ __forceinline__ void block_barrier()
{
    asm volatile("s_waitcnt lgkmcnt(0)\n\ts_barrier" ::: "memory");
}

// ---------------------------------------------------------------------------
// async global->LDS 16B per lane: LDS dst = wave-uniform base + lane*16B
// ---------------------------------------------------------------------------
#if defined(__has_builtin)
#if __has_builtin(__builtin_amdgcn_global_load_lds)
#define HAS_GLD 1
#endif
#endif
#ifndef HAS_GLD
#define HAS_GLD 0
#endif

__device__ __forceinline__ void gld_lds16(const bf16* g, bf16* lds_base)
{
#if HAS_GLD
    __builtin_amdgcn_global_load_lds(
        (const __attribute__((address_space(1))) void*)g,
        (__attribute__((address_space(3))) void*)lds_base, 16, 0, 0);
#else
    *(bf16x8*)(lds_base + (threadIdx.x & 63) * 8) = *(const bf16x8*)g;
#endif
}

// ---------------------------------------------------------------------------
// Weight transpose + fp32->bf16: src (K,N) row-major -> dst (N,K)
// ---------------------------------------------------------------------------
__global__ __launch_bounds__(256)
void transpose_cvt(const float* __restrict__ src, bf16* __restrict__ dst, int K, int N)
{
    __shared__ float t[32][33];
    const int bx = blockIdx.x, by = blockIdx.y, tid = threadIdx.x;
    const int c = tid & 31, r0 = tid >> 5;
#pragma unroll
    for (int p = 0; p < 4; p++) {
        int r = r0 + p * 8;
        t[r][c] = src[(size_t)(by * 32 + r) * N + bx * 32 + c];
    }
    __syncthreads();
#pragma unroll
    for (int p = 0; p < 4; p++) {
        int r = r0 + p * 8;
        dst[(size_t)(bx * 32 + r) * K + by * 32 + c] = (bf16)t[c][r];
    }
}

// ---------------------------------------------------------------------------
// plain fp32 -> bf16 convert, 8 elems/thread
// ---------------------------------------------------------------------------
__global__ __launch_bounds__(256)
void cvt_bf16(const float* __restrict__ src, bf16* __restrict__ dst, int n8)
{
    const int i = blockIdx.x * 256 + threadIdx.x;
    if (i >= n8) return;
    const float4* s = (const float4*)(src + (size_t)i * 8);
    float4 a = s[0], b = s[1];
    bf16x8 o;
    o[0] = (bf16)a.x; o[1] = (bf16)a.y; o[2] = (bf16)a.z; o[3] = (bf16)a.w;
    o[4] = (bf16)b.x; o[5] = (bf16)b.y; o[6] = (bf16)b.z; o[7] = (bf16)b.w;
    *(bf16x8*)(dst + (size_t)i * 8) = o;
}

// ---------------------------------------------------------------------------
// m97-style GEMM: C = A @ B.  A bf16 (rows via ldA), Bt bf16 (N x K, ldB).
// 128x128 tile, BK=32, global_load_lds staging, XCD swizzle (gridDim.x==8).
// Optional A2 for concat-K (gate).
// ---------------------------------------------------------------------------
template<bool TWOA>
__global__ __launch_bounds__(256)
void gemm_a97(const bf16* __restrict__ A1, const bf16* __restrict__ A2,
              const bf16* __restrict__ Bt, float* __restrict__ Cf,
              bf16* __restrict__ Cb, int Kloop, int Ksplit,
              int ldA, int ldA2, int ldB, int ldC,
              long az, long bz, long cz)
{
    __shared__ bf16 Al[128 * 32];
    __shared__ bf16 Bl[128 * 32];

    const int z = blockIdx.z;
    A1 += (size_t)z * az;
    Bt += (size_t)z * bz;
    if (Cf) Cf += (size_t)z * cz;
    if (Cb) Cb += (size_t)z * cz;

    int bx, by;
    {
        const int gy = gridDim.y;
        const int flat = blockIdx.y * gridDim.x + blockIdx.x;
        if ((gy & 7) == 0 && gridDim.x == 8) {
            const int xcd = flat & 7, slot = flat >> 3, mpx = gy >> 3;
            by = xcd * mpx + (slot >> 3);
            bx = slot & 7;
        } else { bx = blockIdx.x; by = blockIdx.y; }
    }

    const int tid = threadIdx.x;
    const int wave = tid >> 6, lane = tid & 63;
    const int m0 = by * 128, n0 = bx * 128;
    const int rl = lane >> 2;
    const int kc = (lane & 3) * 8;
    const int wm = wave >> 1, wn = wave & 1, lm = lane & 15, quad = lane >> 4;

    f32x4 acc[4][4];
#pragma unroll
    for (int i = 0; i < 4; i++)
#pragma unroll
        for (int j = 0; j < 4; j++)
#pragma unroll
            for (int r = 0; r < 4; r++) acc[i][j][r] = 0.f;

    for (int k0 = 0; k0 < Kloop; k0 += 32) {
        const bf16* Ab; int kof, ld;
        if (TWOA && k0 >= Ksplit) { Ab = A2; kof = k0 - Ksplit; ld = ldA2; }
        else                      { Ab = A1; kof = k0;          ld = ldA;  }
        const int r0 = wave * 32 + rl, r1 = r0 + 16;
        gld_lds16(Ab + (size_t)(m0 + r0) * ld + kof + kc, Al + (wave * 32) * 32);
        gld_lds16(Ab + (size_t)(m0 + r1) * ld + kof + kc, Al + (wave * 32 + 16) * 32);
        gld_lds16(Bt + (size_t)(n0 + r0) * ldB + k0 + kc, Bl + (wave * 32) * 32);
        gld_lds16(Bt + (size_t)(n0 + r1) * ldB + k0 + kc, Bl + (wave * 32 + 16) * 32);
        __syncthreads();

        bf16x8 af[4], bfr[4];
#pragma unroll
        for (int i = 0; i < 4; i++)
            af[i] = *(const bf16x8*)&Al[(wm * 64 + i * 16 + lm) * 32 + quad * 8];
#pragma unroll
        for (int j = 0; j < 4; j++)
            bfr[j] = *(const bf16x8*)&Bl[(wn * 64 + j * 16 + lm) * 32 + quad * 8];
#pragma unroll
        for (int i = 0; i < 4; i++)
#pragma unroll
            for (int j = 0; j < 4; j++)
                acc[i][j] = __builtin_amdgcn_mfma_f32_16x16x32_bf16(af[i], bfr[j], acc[i][j], 0, 0, 0);
        __syncthreads();
    }

#pragma unroll
    for (int i = 0; i < 4; i++) {
        const int rbase = m0 + wm * 64 + i * 16 + quad * 4;
#pragma unroll
        for (int j = 0; j < 4; j++) {
            const int c = n0 + wn * 64 + j * 16 + lm;
#pragma unroll
            for (int r = 0; r < 4; r++) {
                const float v = acc[i][j][r];
                const size_t idx = (size_t)(rbase + r) * ldC + c;
                if (Cf) Cf[idx] = v;
                if (Cb) Cb[idx] = (bf16)v;
            }
        }
    }
}

// ---------------------------------------------------------------------------
// Weight-stationary partial-score kernel (unchanged from R4, verified).
// ---------------------------------------------------------------------------
__global__ __launch_bounds__(512, 4)
void score_attn_part(const bf16* __restrict__ Qb, const bf16* __restrict__ Wkb,
                     const float* __restrict__ mk, float* __restrict__ part)
{
    __shared__ bf16 Ul[16 * 1024];   // 32KB [b16][h16][64i] swz ^(((b^h)&7)<<4)

    const int tid  = threadIdx.x;
    const int wave = tid >> 6, lane = tid & 63;
    const int lm = lane & 15, q = lane >> 4;
    const int g  = blockIdx.x;       // b-group: rows [g*128, g*128+128)
    const int c  = blockIdx.y;       // i-chunk: i in [c*64, c*64+64)
    const int i0 = c * 64;
    const int h0 = wave * 2;

    // ---- weight-stationary Wk fragments (16 bf16x8 = 64 VGPR), loaded once
    bf16x8 wk[2][4][2];
#pragma unroll
    for (int hh = 0; hh < 2; hh++)
#pragma unroll
        for (int mt = 0; mt < 4; mt++) {
            const bf16* wp = Wkb + (size_t)(i0 + mt * 16 + lm) * 1024 + (h0 + hh) * 64 + q * 8;
            wk[hh][mt][0] = *(const bf16x8*)(wp);
            wk[hh][mt][1] = *(const bf16x8*)(wp + 32);
        }

    float* pbase = part + ((size_t)c << 20);   // c * 8192*128

    for (int t = 0; t < 8; ++t) {
        const int b0 = g * 128 + t * 16;

        // ---- Q B-frags for this b-tile (rows = b, K = d)
        bf16x8 qf[2][2];
#pragma unroll
        for (int hh = 0; hh < 2; hh++) {
            const bf16* qp = Qb + (size_t)(b0 + lm) * 1024 + (h0 + hh) * 64 + q * 8;
            qf[hh][0] = *(const bf16x8*)(qp);
            qf[hh][1] = *(const bf16x8*)(qp + 32);
        }

        // ---- U-gen: C[i][b] tiles -> Ul
#pragma unroll
        for (int hh = 0; hh < 2; hh++) {
            const int h = h0 + hh;
#pragma unroll
            for (int mt = 0; mt < 4; mt++) {
                f32x4 c4;
                c4[0] = 0.f; c4[1] = 0.f; c4[2] = 0.f; c4[3] = 0.f;
                c4 = __builtin_amdgcn_mfma_f32_16x16x32_bf16(wk[hh][mt][0], qf[hh][0], c4, 0, 0, 0);
                c4 = __builtin_amdgcn_mfma_f32_16x16x32_bf16(wk[hh][mt][1], qf[hh][1], c4, 0, 0, 0);
                bf16x4 o;
                o[0] = (bf16)c4[0]; o[1] = (bf16)c4[1]; o[2] = (bf16)c4[2]; o[3] = (bf16)c4[3];
                *(bf16x4*)((char*)Ul + ((((lm * 16 + h) * 64 + mt * 16 + q * 4) * 2)
                                        ^ (((lm ^ h) & 7) << 4))) = o;
            }
        }
        __syncthreads();

        // ---- score: wave's 2 rows; mk B-frags direct from global (+cvt)
#pragma unroll
        for (int lb = 0; lb < 2; lb++) {
            const int bb = wave * 2 + lb;
            const float* mp = mk + (size_t)(b0 + bb) * 8192 + (lm & 7) * 1024 + i0 + q * 8;
            const f32x4 a0 = *(const f32x4*)(mp);
            const f32x4 a1 = *(const f32x4*)(mp + 4);
            const f32x4 b0v = *(const f32x4*)(mp + 32);
            const f32x4 b1v = *(const f32x4*)(mp + 36);
            bf16x8 m0, m1;
            m0[0] = (bf16)a0[0]; m0[1] = (bf16)a0[1]; m0[2] = (bf16)a0[2]; m0[3] = (bf16)a0[3];
            m0[4] = (bf16)a1[0]; m0[5] = (bf16)a1[1]; m0[6] = (bf16)a1[2]; m0[7] = (bf16)a1[3];
            m1[0] = (bf16)b0v[0]; m1[1] = (bf16)b0v[1]; m1[2] = (bf16)b0v[2]; m1[3] = (bf16)b0v[3];
            m1[4] = (bf16)b1v[0]; m1[5] = (bf16)b1v[1]; m1[6] = (bf16)b1v[2]; m1[7] = (bf16)b1v[3];

            const bf16x8 ua0 = *(const bf16x8*)((char*)Ul +
                ((((bb * 16 + lm) * 64 + q * 8) * 2) ^ (((bb ^ lm) & 7) << 4)));
            const bf16x8 ua1 = *(const bf16x8*)((char*)Ul +
                ((((bb * 16 + lm) * 64 + 32 + q * 8) * 2) ^ (((bb ^ lm) & 7) << 4)));

            f32x4 s4;
            s4[0] = 0.f; s4[1] = 0.f; s4[2] = 0.f; s4[3] = 0.f;
            s4 = __builtin_amdgcn_mfma_f32_16x16x32_bf16(ua0, m0, s4, 0, 0, 0);
            s4 = __builtin_amdgcn_mfma_f32_16x16x32_bf16(ua1, m1, s4, 0, 0, 0);

            // C[h=q*4+r][k=lm&7] for row b0+bb; lm>=8 is a duplicate
            if (lm < 8) {
                float* pp = pbase + (size_t)(b0 + bb) * 128 + lm;
#pragma unroll
                for (int r = 0; r < 4; r++) pp[(q * 4 + r) * 8] = s4[r];
            }
        }
        __syncthreads();
    }
}

// ---------------------------------------------------------------------------
// reduce 16 i-chunk partials + softmax over k -> attn (B x 16 x 8 fp32)
// ---------------------------------------------------------------------------
__global__ __launch_bounds__(256)
void reduce_softmax(const float* __restrict__ part, float* __restrict__ attn)
{
    const int t = blockIdx.x * 256 + threadIdx.x;   // (b*16 + h)
    const float* p = part + (size_t)t * 8;
    float s[8] = {0.f, 0.f, 0.f, 0.f, 0.f, 0.f, 0.f, 0.f};
#pragma unroll
    for (int c = 0; c < 16; ++c) {
        const f32x4 a = *(const f32x4*)(p + ((size_t)c << 20));
        const f32x4 b = *(const f32x4*)(p + ((size_t)c << 20) + 4);
        s[0] += a[0]; s[1] += a[1]; s[2] += a[2]; s[3] += a[3];
        s[4] += b[0]; s[5] += b[1]; s[6] += b[2]; s[7] += b[3];
    }
#pragma unroll
    for (int k = 0; k < 8; k++) s[k] *= 0.125f;     // DH^-0.5
    float mx = s[0];
#pragma unroll
    for (int k = 1; k < 8; k++) mx = fmaxf(mx, s[k]);
    float den = 0.f;
#pragma unroll
    for (int k = 0; k < 8; k++) { s[k] = __expf(s[k] - mx); den += s[k]; }
    const float inv = 1.f / den;
    f32x4 o0, o1;
    o0[0] = s[0] * inv; o0[1] = s[1] * inv; o0[2] = s[2] * inv; o0[3] = s[3] * inv;
    o1[0] = s[4] * inv; o1[1] = s[5] * inv; o1[2] = s[6] * inv; o1[3] = s[7] * inv;
    *(f32x4*)(attn + (size_t)t * 8)     = o0;
    *(f32x4*)(attn + (size_t)t * 8 + 4) = o1;
}

// ---------------------------------------------------------------------------
// Fused apply kernel v8: global_load_lds DMA staging (m97 discipline) + v4's
// dense-consumption (attn B-variants do the k-transpose inside MFMA slots).
// mv slice [16 rows][8 k][32 i] fp32 staged LINEARLY via DMA, double-buffered.
// Per superstep: DMA(sp+1) -> Wm-gen from Vl32[sp] -> lgkm-bar -> OH ->
// __syncthreads (single vmcnt(0)/superstep, after a full compute of cover).
// In-flight mv lives in the DMA engine, not VGPRs (no spill risk).
// ---------------------------------------------------------------------------
__global__ __launch_bounds__(512, 4)
void apply_attn(const float* __restrict__ attn, const float* __restrict__ mv,
                const bf16* __restrict__ Wvt, bf16* __restrict__ OH)
{
    __shared__ float Vl32[2][4096];    // 2x16KB [16 rows][8 k][32 i] fp32, LINEAR
    __shared__ bf16  Wl[16 * 16 * 32]; // 16KB [b][h][32 i] swz ^(((b^h)&7)<<4)

    const int tid  = threadIdx.x;
    const int wave = tid >> 6, lane = tid & 63;
    const int lm = lane & 15, q = lane >> 4;
    const int b0 = blockIdx.x * 16;
    const int h0 = wave * 2;

    // DMA mapping: wave w copies rows 2w, 2w+1 (1KB each = 1 issue).
    // lane l -> k = l>>3, i_local = (l&7)*4  (LDS linear == global slice layout)
    const int gk = lane >> 3, gi4 = (lane & 7) * 4;

    // ---- attn B-frag variants: afv[lb][mt] nonzero only where q==mt (mt 0..1)
    bf16x8 afv[2][2];
#pragma unroll
    for (int lb = 0; lb < 2; lb++) {
        const float* ap = attn + (size_t)(b0 + wave * 2 + lb) * 128 + lm * 8;
        const float4 x = *(const float4*)(ap);
        const float4 y = *(const float4*)(ap + 4);
        bf16 a8[8];
        a8[0] = (bf16)x.x; a8[1] = (bf16)x.y; a8[2] = (bf16)x.z; a8[3] = (bf16)x.w;
        a8[4] = (bf16)y.x; a8[5] = (bf16)y.y; a8[6] = (bf16)y.z; a8[7] = (bf16)y.w;
#pragma unroll
        for (int mt = 0; mt < 2; mt++) {
            bf16x8 t;
#pragma unroll
            for (int j = 0; j < 8; j++) t[j] = (q == mt) ? a8[j] : (bf16)0.f;
            afv[lb][mt] = t;
        }
    }

    f32x4 oacc[2][4];
#pragma unroll
    for (int i = 0; i < 2; i++)
#pragma unroll
        for (int j = 0; j < 4; j++)
#pragma unroll
            for (int r = 0; r < 4; r++) oacc[i][j][r] = 0.f;

    // ---- prologue: DMA slice 0 -> Vl32[0], full drain
#pragma unroll
    for (int m = 0; m < 2; m++) {
        const int row = 2 * wave + m;
        const float* g = mv + (size_t)(b0 + row) * 8192 + gk * 1024 + gi4;
        gld_lds16((const bf16*)g, (bf16*)&Vl32[0][row * 256]);
    }
    __syncthreads();

    for (int sp = 0; sp < 32; ++sp) {
        const int i0 = sp * 32;
        const int ni = (sp == 31) ? 0 : i0 + 32;
        const int cb = sp & 1;

        // ---- DMA slice sp+1 into the other buffer (stays in flight)
#pragma unroll
        for (int m = 0; m < 2; m++) {
            const int row = 2 * wave + m;
            const float* g = mv + (size_t)(b0 + row) * 8192 + gk * 1024 + ni + gi4;
            gld_lds16((const bf16*)g, (bf16*)&Vl32[cb ^ 1][row * 256]);
        }

        // ---- Wm-gen from Vl32[cb]: per row, dense A-frag (q&1 mirrors for
        //      lanes q>=2, zero-multiplied), 2 zero-masked-variant MFMAs.
#pragma unroll
        for (int lb = 0; lb < 2; lb++) {
            const int row = 2 * wave + lb;
            const int il = (q & 1) * 16 + lm;   // i_local in [0,32)
            float v[8];
#pragma unroll
            for (int k = 0; k < 8; k++) v[k] = Vl32[cb][row * 256 + k * 32 + il];
            bf16x8 avf;
#pragma unroll
            for (int k = 0; k < 8; k++) avf[k] = (bf16)v[k];
#pragma unroll
            for (int mt = 0; mt < 2; mt++) {
                f32x4 c;
                c[0] = 0.f; c[1] = 0.f; c[2] = 0.f; c[3] = 0.f;
                c = __builtin_amdgcn_mfma_f32_16x16x32_bf16(avf, afv[lb][mt], c, 0, 0, 0);
                bf16x4 o;
                o[0] = (bf16)c[0]; o[1] = (bf16)c[1]; o[2] = (bf16)c[2]; o[3] = (bf16)c[3];
                // C tile mt: rows i = mt*16 + q*4 + r, col h = lm, for b=row
                *(bf16x4*)((char*)Wl + ((((row * 16 + lm) * 32 + mt * 16 + q * 4) * 2)
                                        ^ (((row ^ lm) & 7) << 4))) = o;
            }
        }
        block_barrier();   // Wl visible (lgkm only; DMA stays in flight)

        // ---- OH: wave's 2 heads vs L2-resident Wv_t (32 k-slots = this slice)
#pragma unroll
        for (int hh = 0; hh < 2; hh++) {
            const int h = h0 + hh;
            const bf16x8 wa = *(const bf16x8*)((char*)Wl +
                ((((lm * 16 + h) * 32 + q * 8) * 2) ^ (((lm ^ h) & 7) << 4)));
#pragma unroll
            for (int dt = 0; dt < 4; dt++) {
                const bf16x8 wb = *(const bf16x8*)(Wvt +
                    (size_t)(h * 64 + dt * 16 + lm) * 1024 + i0 + q * 8);
                oacc[hh][dt] = __builtin_amdgcn_mfma_f32_16x16x32_bf16(wa, wb, oacc[hh][dt], 0, 0, 0);
            }
        }
        __syncthreads();   // vmcnt(0): DMA(sp+1) done; Wl consumed
    }

    // ---- store OH (rows b = q*4+r, cols h*64 + dt*16 + lm)
#pragma unroll
    for (int hh = 0; hh < 2; hh++) {
        const int h = h0 + hh;
#pragma unroll
        for (int dt = 0; dt < 4; dt++) {
#pragma unroll
            for (int r = 0; r < 4; r++)
                OH[(size_t)(b0 + q * 4 + r) * 1024 + h * 64 + dt * 16 + lm] = (bf16)oacc[hh][dt][r];
        }
    }
}

// ---------------------------------------------------------------------------
// sigmoid gate + residual + LayerNorm. One block per row.
// ---------------------------------------------------------------------------
__global__ __launch_bounds__(256)
void gate_ln_kernel(const float* __restrict__ hs, const float* __restrict__ mo,
                    const float* __restrict__ z,  const float* __restrict__ bg,
                    const float* __restrict__ lng, const float* __restrict__ lnb,
                    float* __restrict__ out)
{
    __shared__ float s1[4], s2[4];
    const int tid = threadIdx.x;
    const size_t base = (size_t)blockIdx.x * 1024 + tid * 4;

    const float4 h4 = *(const float4*)&hs[base];
    const float4 m4 = *(const float4*)&mo[base];
    const float4 z4 = *(const float4*)&z[base];
    const float4 bg4 = *(const float4*)&bg[tid * 4];

    float a[4];
    {
        const float g0 = 1.f / (1.f + __expf(-(z4.x + bg4.x)));
        const float g1 = 1.f / (1.f + __expf(-(z4.y + bg4.y)));
        const float g2 = 1.f / (1.f + __expf(-(z4.z + bg4.z)));
        const float g3 = 1.f / (1.f + __expf(-(z4.w + bg4.w)));
        a[0] = h4.x + g0 * m4.x;
        a[1] = h4.y + g1 * m4.y;
        a[2] = h4.z + g2 * m4.z;
        a[3] = h4.w + g3 * m4.w;
    }
    float sum = a[0] + a[1] + a[2] + a[3];
    float sq  = a[0]*a[0] + a[1]*a[1] + a[2]*a[2] + a[3]*a[3];
#pragma unroll
    for (int off = 32; off >= 1; off >>= 1) {
        sum += __shfl_xor(sum, off);
        sq  += __shfl_xor(sq,  off);
    }
    const int wave = tid >> 6;
    if ((tid & 63) == 0) { s1[wave] = sum; s2[wave] = sq; }
    __syncthreads();
    const float mean = (s1[0] + s1[1] + s1[2] + s1[3]) * (1.f / 1024.f);
    const float var  = (s2[0] + s2[1] + s2[2] + s2[3]) * (1.f / 1024.f) - mean * mean;
    const float inv  = rsqrtf(var + 1e-5f);

    const float4 g4 = *(const float4*)&lng[tid * 4];
    const float4 b4 = *(const float4*)&lnb[tid * 4];
    float4 o;
    o.x = (a[0] - mean) * inv * g4.x + b4.x;
    o.y = (a[1] - mean) * inv * g4.y + b4.y;
    o.z = (a[2] - mean) * inv * g4.z + b4.z;
    o.w = (a[3] - mean) * inv * g4.w + b4.w;
    *(float4*)&out[base] = o;
}

// ---------------------------------------------------------------------------
extern "C" void kernel_launch(void* const* d_in, const int* in_sizes, int n_in,
                              void* d_out, int out_size, void* d_ws, size_t ws_size,
                              hipStream_t stream)
{
    const float* hs  = (const float*)d_in[0];
    const float* mk  = (const float*)d_in[1];
    const float* mv  = (const float*)d_in[2];
    const float* Wq  = (const float*)d_in[3];
    const float* Wk  = (const float*)d_in[4];
    const float* Wv  = (const float*)d_in[5];
    const float* Wo  = (const float*)d_in[6];
    const float* Wg  = (const float*)d_in[7];
    const float* bg  = (const float*)d_in[8];
    const float* lng = (const float*)d_in[9];
    const float* lnb = (const float*)d_in[10];
    float* out = (float*)d_out;

    const int B = 8192;
    const dim3 tb(256);

    char* ws = (char*)d_ws;
    bf16*  Wq_t = (bf16*)(ws);                        // 2 MB  (1024x1024, N x K)
    bf16*  Wv_t = (bf16*)(ws + ((size_t)2  << 20));   // 2 MB
    bf16*  Wo_t = (bf16*)(ws + ((size_t)4  << 20));   // 2 MB
    bf16*  Wg_t = (bf16*)(ws + ((size_t)6  << 20));   // 4 MB  (1024x2048)
    bf16*  Wk_b = (bf16*)(ws + ((size_t)10 << 20));   // 2 MB  (1024x1024, NOT transposed)
    bf16*  hs_b = (bf16*)(ws + ((size_t)12 << 20));   // 16 MB (8192x1024)
    bf16*  Qb   = (bf16*)(ws + ((size_t)28 << 20));   // 16 MB
    bf16*  OH   = (bf16*)(ws + ((size_t)44 << 20));   // 16 MB
    float* Mo   = (float*)(ws + ((size_t)60 << 20));  // 32 MB
    bf16*  Mo_b = (bf16*)(ws + ((size_t)92 << 20));   // 16 MB
    float* Zb   = (float*)(ws + ((size_t)108 << 20)); // 32 MB
    float* At   = (float*)(ws + ((size_t)140 << 20)); // 4 MB  (8192x16x8 fp32)
    float* Atp  = (float*)(ws + ((size_t)144 << 20)); // 64 MB (16 x 8192x16x8 fp32)

    transpose_cvt<<<dim3(32, 32), tb, 0, stream>>>(Wq, Wq_t, 1024, 1024);
    transpose_cvt<<<dim3(32, 32), tb, 0, stream>>>(Wv, Wv_t, 1024, 1024);
    transpose_cvt<<<dim3(32, 32), tb, 0, stream>>>(Wo, Wo_t, 1024, 1024);
    transpose_cvt<<<dim3(32, 64), tb, 0, stream>>>(Wg, Wg_t, 2048, 1024);
    cvt_bf16<<<dim3(1024 * 1024 / 8 / 256), tb, 0, stream>>>(Wk, Wk_b, 1024 * 1024 / 8);
    cvt_bf16<<<dim3(B * 1024 / 8 / 256), tb, 0, stream>>>(hs, hs_b, B * 1024 / 8);

    // Q = hs @ Wq -> bf16 (B x 1024)
    gemm_a97<false><<<dim3(8, 64, 1), tb, 0, stream>>>(
        hs_b, nullptr, Wq_t, nullptr, Qb,
        1024, 1024, 1024, 0, 1024, 1024, 0, 0, 0);
    // weight-stationary partial scores (16 i-chunks x 64 b-groups)
    score_attn_part<<<dim3(64, 16), dim3(512), 0, stream>>>(Qb, Wk_b, mk, Atp);
    // reduce chunks + softmax -> attn
    reduce_softmax<<<dim3(512), tb, 0, stream>>>(Atp, At);
    // fused: W_mix-gen + V-proj -> OH (B x 1024 bf16)
    apply_attn<<<dim3(B / 16), dim3(512), 0, stream>>>(At, mv, Wv_t, OH);
    // memory_out = OH @ Wo -> fp32 Mo + bf16 Mo_b
    gemm_a97<false><<<dim3(8, 64, 1), tb, 0, stream>>>(
        OH, nullptr, Wo_t, Mo, Mo_b,
        1024, 1024, 1024, 0, 1024, 1024, 0, 0, 0);
    // z = [hs, Mo] @ Wg -> fp32
    gemm_a97<true><<<dim3(8, 64, 1), tb, 0, stream>>>(
        hs_b, Mo_b, Wg_t, Zb, nullptr,
        2048, 1024, 1024, 1024, 2048, 1024, 0, 0, 0);
    // gate + residual + LayerNorm
    gate_ln_kernel<<<dim3(B), tb, 0, stream>>>(
        hs, Mo, Zb, bg, lng, lnb, out);
}